// Round 2
// baseline (209.574 us; speedup 1.0000x reference)
//
#include <hip/hip_runtime.h>
#include <stdint.h>

#define BATCH 8
#define NN 4096
#define CC 64
#define MASKV -1.0e30f
#define LOG2E 1.4426950408889634f

typedef _Float16 half8 __attribute__((ext_vector_type(8)));
typedef __fp16 fp16x2 __attribute__((ext_vector_type(2)));
typedef float f32x4 __attribute__((ext_vector_type(4)));

// ------------------------------------------------------------------
// Projection: q (fp16 hi+lo, pre-scaled by log2e), k (fp16), vT (fp16,
// [b][c][n]). Split-compensated fp16 MFMA -> only fp16 STORAGE
// rounding (2^-11) survives into the attention matmuls. (unchanged)
// ------------------------------------------------------------------
__global__ __launch_bounds__(256) void gat_proj(
    const float* __restrict__ X, const float* __restrict__ W0,
    const float* __restrict__ Wq, const float* __restrict__ Wk,
    _Float16* __restrict__ qh, _Float16* __restrict__ ql,
    _Float16* __restrict__ kb, _Float16* __restrict__ vt)
{
    __shared__ alignas(16) _Float16 WTh[3][64][72];   // [mat][c_out][c_in], +8 pad
    __shared__ alignas(16) _Float16 WTl[3][64][72];
    const int t = threadIdx.x;
    const float* Ws[3] = {W0, Wq, Wk};
    for (int e = t; e < 4096; e += 256) {
        int k = e >> 6, c = e & 63;
        #pragma unroll
        for (int m = 0; m < 3; ++m) {
            float w = Ws[m][e];
            _Float16 hi = (_Float16)w;
            WTh[m][c][k] = hi;
            WTl[m][c][k] = (_Float16)(w - (float)hi);
        }
    }
    __syncthreads();
    const int lane = t & 63, wv = t >> 6;
    const int cl = lane & 15, g = lane >> 4;
    {
        int tile = blockIdx.x * 4 + wv;               // 2048 tiles of 16 rows
        int gr = tile * 16;
        const float* xr = X + (size_t)(gr + cl) * CC;
        half8 xh[2], xl[2];
        #pragma unroll
        for (int kf = 0; kf < 2; ++kf) {
            f32x4 a0 = *(const f32x4*)(xr + g*8 + kf*32);
            f32x4 a1 = *(const f32x4*)(xr + g*8 + kf*32 + 4);
            half8 h, l;
            #pragma unroll
            for (int j = 0; j < 4; ++j) {
                _Float16 h0 = (_Float16)a0[j], h1 = (_Float16)a1[j];
                h[j]   = h0; l[j]   = (_Float16)(a0[j] - (float)h0);
                h[j+4] = h1; l[j+4] = (_Float16)(a1[j] - (float)h1);
            }
            xh[kf] = h; xl[kf] = l;
        }
        // q and k: D[row][c_out] = X * W
        #pragma unroll
        for (int mat = 1; mat <= 2; ++mat) {
            #pragma unroll
            for (int nt = 0; nt < 4; ++nt) {
                f32x4 acc = {0.f, 0.f, 0.f, 0.f};
                #pragma unroll
                for (int kf = 0; kf < 2; ++kf) {
                    half8 bh = *(const half8*)&WTh[mat][nt*16 + cl][g*8 + kf*32];
                    half8 bl = *(const half8*)&WTl[mat][nt*16 + cl][g*8 + kf*32];
                    acc = __builtin_amdgcn_mfma_f32_16x16x32_f16(xh[kf], bh, acc, 0, 0, 0);
                    acc = __builtin_amdgcn_mfma_f32_16x16x32_f16(xl[kf], bh, acc, 0, 0, 0);
                    acc = __builtin_amdgcn_mfma_f32_16x16x32_f16(xh[kf], bl, acc, 0, 0, 0);
                }
                #pragma unroll
                for (int i = 0; i < 4; ++i) {
                    size_t off = (size_t)(gr + 4*g + i) * CC + nt*16 + cl;
                    if (mat == 1) {
                        float qs = acc[i] * LOG2E;        // fold log2e for exp2 softmax
                        _Float16 hi = (_Float16)qs;
                        qh[off] = hi;
                        ql[off] = (_Float16)(qs - (float)hi);
                    } else {
                        kb[off] = (_Float16)acc[i];
                    }
                }
            }
        }
        // vT: D[c_out][row] = W^T * X^T -> [b][c][n] layout
        {
            int b = gr >> 12, n0 = gr & (NN - 1);
            #pragma unroll
            for (int mt = 0; mt < 4; ++mt) {
                f32x4 acc = {0.f, 0.f, 0.f, 0.f};
                #pragma unroll
                for (int kf = 0; kf < 2; ++kf) {
                    half8 ah = *(const half8*)&WTh[0][mt*16 + cl][g*8 + kf*32];
                    half8 al = *(const half8*)&WTl[0][mt*16 + cl][g*8 + kf*32];
                    acc = __builtin_amdgcn_mfma_f32_16x16x32_f16(ah, xh[kf], acc, 0, 0, 0);
                    acc = __builtin_amdgcn_mfma_f32_16x16x32_f16(al, xh[kf], acc, 0, 0, 0);
                    acc = __builtin_amdgcn_mfma_f32_16x16x32_f16(ah, xl[kf], acc, 0, 0, 0);
                }
                #pragma unroll
                for (int i = 0; i < 4; ++i) {
                    int co = mt*16 + 4*g + i;
                    vt[((size_t)b * CC + co) * NN + n0 + cl] = (_Float16)acc[i];
                }
            }
        }
    }
}

// ------------------------------------------------------------------
// Adjacency -> fragment-layout byte-masks (diagonal forced).
// AM[(row*64 + chunk)*4 + g] is one uint4; component kt holds the
// 4 byte-masks (0x00/0xFF) of keys chunk*64 + kt*16 + 4g + {0..3} --
// exactly the element order lane (cl=row%16, g) produces in gat_attn.
// One block per row; thread t = chunk*4 + g.
// ------------------------------------------------------------------
__global__ __launch_bounds__(256) void gat_mask(const int* __restrict__ A,
                                                uint4* __restrict__ AM)
{
    const int r = blockIdx.x;
    const int t = threadIdx.x;
    const int kc = t >> 2, g = t & 3;
    unsigned w[4];
    #pragma unroll
    for (int kt = 0; kt < 4; ++kt) {
        const int k0 = kc*64 + kt*16 + 4*g;
        int4 a = *(const int4*)(A + (size_t)r * NN + k0);
        unsigned m = 0;
        m |= (a.x != 0 || k0     == r) ? 0x000000FFu : 0u;
        m |= (a.y != 0 || k0 + 1 == r) ? 0x0000FF00u : 0u;
        m |= (a.z != 0 || k0 + 2 == r) ? 0x00FF0000u : 0u;
        m |= (a.w != 0 || k0 + 3 == r) ? 0xFF000000u : 0u;
        w[kt] = m;
    }
    AM[(size_t)r * 256 + t] = make_uint4(w[0], w[1], w[2], w[3]);
}

// ------------------------------------------------------------------
// Flash attention, split-K x4.
//  * Masked row-max computed in packed-fp16 domain: scores packed via
//    cvt_pkrtz, masked lanes forced to fp16 -inf with one v_bfi_b32
//    per word ((hm & s) | (~hm & 0xFC00FC00)), then a 7-op
//    v_pk_max_f16 tree. (Round-1's superset max underflowed fp16 when
//    the best masked-in key sat far below the unmasked max -> FIXED.)
//  * Mask applied post-exp as bitwise AND on packed fp16 P pairs; the
//    fp16-rounded max cancels exactly in the split-K combine.
//  * l summed from the masked fp16 P words via v_pk_add_f16.
//  * LDS XOR-swizzle (byte ^= (row&7)<<4, 128B rows, no pads).
//  * s_setprio(1) around MFMA clusters.
// ------------------------------------------------------------------
__global__ __launch_bounds__(256) void gat_attn(
    const _Float16* __restrict__ qh, const _Float16* __restrict__ ql,
    const _Float16* __restrict__ kf16, const _Float16* __restrict__ vtb,
    const uint4* __restrict__ AM,
    _Float16* __restrict__ po, float2* __restrict__ pml)
{
    __shared__ alignas(16) _Float16 Kt[64][64];       // [key][c_in], swizzled
    __shared__ alignas(16) _Float16 Vt[64][64];       // [c_out][key], swizzled
    __shared__ alignas(16) _Float16 Ps[4][32][64];    // per-wave [qrow][key], swizzled
    const int t = threadIdx.x;
    const int lane = t & 63, wv = t >> 6;
    const int cl = lane & 15, g = lane >> 4;
    const int blk = blockIdx.x;        // 1024
    const int b  = blk & 7;            // batch == XCD (blk % 8 dispatch)
    const int sp = (blk >> 3) & 3;     // key split
    const int qb = blk >> 5;           // q tile 0..31
    const int Q0 = qb * 128 + wv * 32;
    const int c0 = sp * 16;            // first 64-key chunk of this split
    const int swz = (cl & 7) << 4;     // read-side XOR (row%8 == cl%8)

    // loop-invariant swizzled staging destinations (row = t>>3, +32)
    const int soff = (((t >> 3) * 128 + (t & 7) * 16) ^ (((t >> 3) & 7) << 4));
    char* const kd0 = (char*)Kt + soff;
    char* const kd1 = (char*)Kt + soff + 32 * 128;    // (row+32)&7 == row&7
    char* const vd0 = (char*)Vt + soff;
    char* const vd1 = (char*)Vt + soff + 32 * 128;
    char* const psb = (char*)&Ps[wv][0][0];

    half8 qfh[2][2], qfl[2][2];
    #pragma unroll
    for (int qt = 0; qt < 2; ++qt) {
        const _Float16* qrh = qh + ((size_t)b * NN + Q0 + qt*16 + cl) * CC;
        const _Float16* qrl = ql + ((size_t)b * NN + Q0 + qt*16 + cl) * CC;
        qfh[qt][0] = *(const half8*)(qrh + g*8);
        qfh[qt][1] = *(const half8*)(qrh + g*8 + 32);
        qfl[qt][0] = *(const half8*)(qrl + g*8);
        qfl[qt][1] = *(const half8*)(qrl + g*8 + 32);
    }
    const _Float16* kg = kf16 + (size_t)b * NN * CC;
    const _Float16* vg = vtb + (size_t)b * CC * NN;

    f32x4 o[2][4] = {};
    float m_run[2] = {MASKV, MASKV}, l_run[2] = {0.f, 0.f};

    uint4 pk0, pk1, pv0, pv1, pa, pb;
    auto loadchunk = [&](int kc) {                    // kc = global chunk id
        const uint4* ks = (const uint4*)(kg + (size_t)kc * 64 * CC);
        pk0 = ks[t];
        pk1 = ks[t + 256];
        const _Float16* vs = vg + kc * 64;
        pv0 = *(const uint4*)(vs + (size_t)(t >> 3) * NN + (t & 7) * 8);
        pv1 = *(const uint4*)(vs + (size_t)((t >> 3) + 32) * NN + (t & 7) * 8);
        pa = AM[(size_t)(Q0 + cl)      * 256 + kc * 4 + g];
        pb = AM[(size_t)(Q0 + 16 + cl) * 256 + kc * 4 + g];
    };
    loadchunk(c0);

    auto pkmax = [](unsigned a, unsigned b) {
        unsigned d;
        asm("v_pk_max_f16 %0, %1, %2" : "=v"(d) : "v"(a), "v"(b));
        return d;
    };

    for (int kc = 0; kc < 16; ++kc) {
        __syncthreads();                 // previous tile's consumers done
        *(uint4*)kd0 = pk0;
        *(uint4*)kd1 = pk1;
        *(uint4*)vd0 = pv0;
        *(uint4*)vd1 = pv1;
        const uint4 ca = pa, cb = pb;
        __syncthreads();                 // tile ready
        if (kc < 15) loadchunk(c0 + kc + 1);   // overlap with compute

        // S^T tiles: D[key][qrow]; q hi/lo fp16 (K frag reused)
        __builtin_amdgcn_s_setprio(1);
        f32x4 sc[2][4] = {};
        #pragma unroll
        for (int kt = 0; kt < 4; ++kt) {
            #pragma unroll
            for (int kf = 0; kf < 2; ++kf) {
                half8 ka = *(const half8*)((char*)Kt +
                    ((((kt*16 + cl) * 128) + g*16 + kf*64) ^ swz));
                sc[0][kt] = __builtin_amdgcn_mfma_f32_16x16x32_f16(ka, qfh[0][kf], sc[0][kt], 0, 0, 0);
                sc[0][kt] = __builtin_amdgcn_mfma_f32_16x16x32_f16(ka, qfl[0][kf], sc[0][kt], 0, 0, 0);
                sc[1][kt] = __builtin_amdgcn_mfma_f32_16x16x32_f16(ka, qfh[1][kf], sc[1][kt], 0, 0, 0);
                sc[1][kt] = __builtin_amdgcn_mfma_f32_16x16x32_f16(ka, qfl[1][kf], sc[1][kt], 0, 0, 0);
            }
        }
        __builtin_amdgcn_s_setprio(0);

        // softmax (exp2 domain); lane owns q-row qt*16+cl.
        #pragma unroll
        for (int qt = 0; qt < 2; ++qt) {
            const uint4 wm = qt ? cb : ca;
            const unsigned am[4] = {wm.x, wm.y, wm.z, wm.w};
            // byte-masks -> halfword AND masks (1 v_perm each)
            unsigned hm[8];
            #pragma unroll
            for (int kt = 0; kt < 4; ++kt) {
                hm[2*kt]   = __builtin_amdgcn_perm(0u, am[kt], 0x01010000u);
                hm[2*kt+1] = __builtin_amdgcn_perm(0u, am[kt], 0x03030202u);
            }
            float sv[16];
            #pragma unroll
            for (int j = 0; j < 16; ++j) {
                float x = sc[qt][j >> 2][j & 3];
                sv[j] = fmaxf(x, 0.01f * x);          // leaky_relu
            }
            // masked row-max in packed fp16: (hm & s) | (~hm & -inf)
            union UH { unsigned u; fp16x2 h; };
            unsigned sm[8];
            #pragma unroll
            for (int kt = 0; kt < 4; ++kt) {
                UH s0, s1;
                s0.h = __builtin_amdgcn_cvt_pkrtz(sv[4*kt + 0], sv[4*kt + 1]);
                s1.h = __builtin_amdgcn_cvt_pkrtz(sv[4*kt + 2], sv[4*kt + 3]);
                sm[2*kt]   = (hm[2*kt]   & s0.u) | (~hm[2*kt]   & 0xFC00FC00u);
                sm[2*kt+1] = (hm[2*kt+1] & s1.u) | (~hm[2*kt+1] & 0xFC00FC00u);
            }
            unsigned tm = pkmax(
                pkmax(pkmax(sm[0], sm[1]), pkmax(sm[2], sm[3])),
                pkmax(pkmax(sm[4], sm[5]), pkmax(sm[6], sm[7])));
            UH tmu; tmu.u = tm;
            float mx = fmaxf((float)tmu.h[0], (float)tmu.h[1]);
            mx = fmaxf(mx, __shfl_xor(mx, 16));
            mx = fmaxf(mx, __shfl_xor(mx, 32));
            if (__any(mx > m_run[qt])) {                   // wave-uniform skip
                float nm = fmaxf(m_run[qt], mx);
                float alpha = __builtin_amdgcn_exp2f(m_run[qt] - nm);
                m_run[qt] = nm;
                l_run[qt] *= alpha;
                #pragma unroll
                for (int ct = 0; ct < 4; ++ct) o[qt][ct] *= alpha;
            }
            float p[16];
            #pragma unroll
            for (int j = 0; j < 16; ++j)
                p[j] = __builtin_amdgcn_exp2f(sv[j] - m_run[qt]);
            UH zz; zz.u = 0u;
            fp16x2 acc2 = zz.h;
            #pragma unroll
            for (int kt = 0; kt < 4; ++kt) {
                UH w0, w1;
                w0.h = __builtin_amdgcn_cvt_pkrtz(p[kt*4 + 0], p[kt*4 + 1]);
                w1.h = __builtin_amdgcn_cvt_pkrtz(p[kt*4 + 2], p[kt*4 + 3]);
                w0.u &= hm[2*kt];                      // masked (incl. inf) -> 0
                w1.u &= hm[2*kt+1];
                uint2 pw = {w0.u, w1.u};
                *(uint2*)(psb + ((((qt*16 + cl) * 128) + kt*32 + g*8) ^ swz)) = pw;
                acc2 += w0.h + w1.h;                   // v_pk_add_f16 tree
            }
            l_run[qt] += (float)acc2[0] + (float)acc2[1];
        }
        __builtin_amdgcn_wave_barrier();   // same-wave DS in-order; fence scheduler

        half8 pf[2][2];
        #pragma unroll
        for (int qt = 0; qt < 2; ++qt) {
            pf[qt][0] = *(const half8*)(psb + ((((qt*16 + cl) * 128) + g*16) ^ swz));
            pf[qt][1] = *(const half8*)(psb + ((((qt*16 + cl) * 128) + g*16 + 64) ^ swz));
        }
        // O^T += V^T * P^T
        __builtin_amdgcn_s_setprio(1);
        #pragma unroll
        for (int ct = 0; ct < 4; ++ct) {
            half8 vf0 = *(const half8*)((char*)Vt + ((((ct*16 + cl) * 128) + g*16) ^ swz));
            half8 vf1 = *(const half8*)((char*)Vt + ((((ct*16 + cl) * 128) + g*16 + 64) ^ swz));
            #pragma unroll
            for (int qt = 0; qt < 2; ++qt) {
                o[qt][ct] = __builtin_amdgcn_mfma_f32_16x16x32_f16(vf0, pf[qt][0], o[qt][ct], 0, 0, 0);
                o[qt][ct] = __builtin_amdgcn_mfma_f32_16x16x32_f16(vf1, pf[qt][1], o[qt][ct], 0, 0, 0);
            }
        }
        __builtin_amdgcn_s_setprio(0);
    }

    // epilogue: store UNNORMALIZED fp16 partial o + (m, l) for combine
    #pragma unroll
    for (int qt = 0; qt < 2; ++qt) {
        float lt = l_run[qt];
        lt += __shfl_xor(lt, 16);
        lt += __shfl_xor(lt, 32);
        size_t base = (size_t)sp * (BATCH * NN) + (size_t)b * NN + Q0 + qt*16 + cl;
        _Float16* orow = po + base * 64;
        #pragma unroll
        for (int ct = 0; ct < 4; ++ct) {
            union { fp16x2 h; unsigned u; } o0u, o1u;
            o0u.h = __builtin_amdgcn_cvt_pkrtz(o[qt][ct][0], o[qt][ct][1]);
            o1u.h = __builtin_amdgcn_cvt_pkrtz(o[qt][ct][2], o[qt][ct][3]);
            uint2 ow = {o0u.u, o1u.u};
            *(uint2*)(orow + ct*16 + 4*g) = ow;
        }
        if (g == 0) pml[base] = make_float2(m_run[qt], lt);
    }
}

// ------------------------------------------------------------------
// Combine the 4 split-K partials: out = sum_s w_s*o_s / sum_s w_s*l_s,
// w_s = exp2(m_s - max_s m_s). Fully-masked splits have l=0, o=0.
// ------------------------------------------------------------------
__global__ __launch_bounds__(256) void gat_comb(
    const _Float16* __restrict__ po, const float2* __restrict__ pml,
    float* __restrict__ out)
{
    int gid = blockIdx.x * 256 + threadIdx.x;     // 131072 threads
    int row = gid >> 2;                            // 0..32767 (b*N + n)
    int col = (gid & 3) * 16;
    float2 ml[4];
    float Mx = MASKV;
    #pragma unroll
    for (int s = 0; s < 4; ++s) {
        ml[s] = pml[s * (BATCH * NN) + row];
        Mx = fmaxf(Mx, ml[s].x);
    }
    float w[4], den = 0.f;
    #pragma unroll
    for (int s = 0; s < 4; ++s) {
        w[s] = __builtin_amdgcn_exp2f(ml[s].x - Mx);
        den += w[s] * ml[s].y;
    }
    float inv = 1.0f / den;                        // diag guarantees den > 0
    float acc[16] = {};
    #pragma unroll
    for (int s = 0; s < 4; ++s) {
        const _Float16* p = po + ((size_t)s * (BATCH * NN) + row) * 64 + col;
        float a = w[s] * inv;
        half8 v0 = *(const half8*)(p);
        half8 v1 = *(const half8*)(p + 8);
        #pragma unroll
        for (int j = 0; j < 8; ++j) {
            acc[j]     += a * (float)v0[j];
            acc[j + 8] += a * (float)v1[j];
        }
    }
    float* op = out + (size_t)row * 64 + col;
    #pragma unroll
    for (int i = 0; i < 4; ++i) {
        f32x4 r = {acc[4*i], acc[4*i+1], acc[4*i+2], acc[4*i+3]};
        *(f32x4*)(op + i*4) = r;
    }
}

extern "C" void kernel_launch(void* const* d_in, const int* in_sizes, int n_in,
                              void* d_out, int out_size, void* d_ws, size_t ws_size,
                              hipStream_t stream) {
    const float* X  = (const float*)d_in[0];
    const int*   A  = (const int*)d_in[1];
    const float* W0 = (const float*)d_in[2];
    const float* Wq = (const float*)d_in[3];
    const float* Wk = (const float*)d_in[4];
    float* out = (float*)d_out;
    char* ws = (char*)d_ws;
    const size_t SZ = (size_t)BATCH * NN * CC * 2;        // 4 MB per fp16 tensor
    _Float16* qh  = (_Float16*)(ws);
    _Float16* ql  = (_Float16*)(ws + SZ);
    _Float16* kbf = (_Float16*)(ws + 2*SZ);
    _Float16* vtb = (_Float16*)(ws + 3*SZ);
    uint4* AMp    = (uint4*)(ws + 4*SZ);                       // 16 MB masks
    _Float16* po  = (_Float16*)(ws + 4*SZ + (size_t)16*1024*1024);   // 16 MB
    float2* pml   = (float2*)(ws + 4*SZ + (size_t)32*1024*1024);     // 1 MB

    hipLaunchKernelGGL(gat_proj, dim3(512),  dim3(256), 0, stream, X, W0, Wq, Wk, qh, ql, kbf, vtb);
    hipLaunchKernelGGL(gat_mask, dim3(4096), dim3(256), 0, stream, A, AMp);
    hipLaunchKernelGGL(gat_attn, dim3(1024), dim3(256), 0, stream, qh, ql, kbf, vtb,
                       AMp, po, pml);
    hipLaunchKernelGGL(gat_comb, dim3(512),  dim3(256), 0, stream, po, pml, out);
}

// Round 3
// 205.675 us; speedup vs baseline: 1.0190x; 1.0190x over previous
//
#include <hip/hip_runtime.h>
#include <stdint.h>

#define BATCH 8
#define NN 4096
#define CC 64
#define MASKV -1.0e30f
#define LOG2E 1.4426950408889634f

typedef _Float16 half8 __attribute__((ext_vector_type(8)));
typedef __fp16 fp16x2 __attribute__((ext_vector_type(2)));
typedef float f32x4 __attribute__((ext_vector_type(4)));

// ------------------------------------------------------------------
// Projection: q (fp16 hi+lo, pre-scaled by log2e), k (fp16), vT (fp16,
// [b][c][n]). Split-compensated fp16 MFMA -> only fp16 STORAGE
// rounding (2^-11) survives into the attention matmuls. (unchanged)
// ------------------------------------------------------------------
__global__ __launch_bounds__(256) void gat_proj(
    const float* __restrict__ X, const float* __restrict__ W0,
    const float* __restrict__ Wq, const float* __restrict__ Wk,
    _Float16* __restrict__ qh, _Float16* __restrict__ ql,
    _Float16* __restrict__ kb, _Float16* __restrict__ vt)
{
    __shared__ alignas(16) _Float16 WTh[3][64][72];   // [mat][c_out][c_in], +8 pad
    __shared__ alignas(16) _Float16 WTl[3][64][72];
    const int t = threadIdx.x;
    const float* Ws[3] = {W0, Wq, Wk};
    for (int e = t; e < 4096; e += 256) {
        int k = e >> 6, c = e & 63;
        #pragma unroll
        for (int m = 0; m < 3; ++m) {
            float w = Ws[m][e];
            _Float16 hi = (_Float16)w;
            WTh[m][c][k] = hi;
            WTl[m][c][k] = (_Float16)(w - (float)hi);
        }
    }
    __syncthreads();
    const int lane = t & 63, wv = t >> 6;
    const int cl = lane & 15, g = lane >> 4;
    {
        int tile = blockIdx.x * 4 + wv;               // 2048 tiles of 16 rows
        int gr = tile * 16;
        const float* xr = X + (size_t)(gr + cl) * CC;
        half8 xh[2], xl[2];
        #pragma unroll
        for (int kf = 0; kf < 2; ++kf) {
            f32x4 a0 = *(const f32x4*)(xr + g*8 + kf*32);
            f32x4 a1 = *(const f32x4*)(xr + g*8 + kf*32 + 4);
            half8 h, l;
            #pragma unroll
            for (int j = 0; j < 4; ++j) {
                _Float16 h0 = (_Float16)a0[j], h1 = (_Float16)a1[j];
                h[j]   = h0; l[j]   = (_Float16)(a0[j] - (float)h0);
                h[j+4] = h1; l[j+4] = (_Float16)(a1[j] - (float)h1);
            }
            xh[kf] = h; xl[kf] = l;
        }
        // q and k: D[row][c_out] = X * W
        #pragma unroll
        for (int mat = 1; mat <= 2; ++mat) {
            #pragma unroll
            for (int nt = 0; nt < 4; ++nt) {
                f32x4 acc = {0.f, 0.f, 0.f, 0.f};
                #pragma unroll
                for (int kf = 0; kf < 2; ++kf) {
                    half8 bh = *(const half8*)&WTh[mat][nt*16 + cl][g*8 + kf*32];
                    half8 bl = *(const half8*)&WTl[mat][nt*16 + cl][g*8 + kf*32];
                    acc = __builtin_amdgcn_mfma_f32_16x16x32_f16(xh[kf], bh, acc, 0, 0, 0);
                    acc = __builtin_amdgcn_mfma_f32_16x16x32_f16(xl[kf], bh, acc, 0, 0, 0);
                    acc = __builtin_amdgcn_mfma_f32_16x16x32_f16(xh[kf], bl, acc, 0, 0, 0);
                }
                #pragma unroll
                for (int i = 0; i < 4; ++i) {
                    size_t off = (size_t)(gr + 4*g + i) * CC + nt*16 + cl;
                    if (mat == 1) {
                        float qs = acc[i] * LOG2E;        // fold log2e for exp2 softmax
                        _Float16 hi = (_Float16)qs;
                        qh[off] = hi;
                        ql[off] = (_Float16)(qs - (float)hi);
                    } else {
                        kb[off] = (_Float16)acc[i];
                    }
                }
            }
        }
        // vT: D[c_out][row] = W^T * X^T -> [b][c][n] layout
        {
            int b = gr >> 12, n0 = gr & (NN - 1);
            #pragma unroll
            for (int mt = 0; mt < 4; ++mt) {
                f32x4 acc = {0.f, 0.f, 0.f, 0.f};
                #pragma unroll
                for (int kf = 0; kf < 2; ++kf) {
                    half8 ah = *(const half8*)&WTh[0][mt*16 + cl][g*8 + kf*32];
                    half8 al = *(const half8*)&WTl[0][mt*16 + cl][g*8 + kf*32];
                    acc = __builtin_amdgcn_mfma_f32_16x16x32_f16(ah, xh[kf], acc, 0, 0, 0);
                    acc = __builtin_amdgcn_mfma_f32_16x16x32_f16(al, xh[kf], acc, 0, 0, 0);
                    acc = __builtin_amdgcn_mfma_f32_16x16x32_f16(ah, xl[kf], acc, 0, 0, 0);
                }
                #pragma unroll
                for (int i = 0; i < 4; ++i) {
                    int co = mt*16 + 4*g + i;
                    vt[((size_t)b * CC + co) * NN + n0 + cl] = (_Float16)acc[i];
                }
            }
        }
    }
}

// ------------------------------------------------------------------
// Adjacency -> bitmask (forced diagonal). One block per row; each
// thread packs 16 keys (4x int4 loads) into one u16 store. Compact
// 2 MB stream -> L2-resident per XCD (round-0 proven).
// ------------------------------------------------------------------
__global__ __launch_bounds__(256) void gat_mask(const int* __restrict__ A,
                                                unsigned short* __restrict__ M16)
{
    const int row = blockIdx.x;
    const int w16 = threadIdx.x;
    const int4* ap = (const int4*)(A + (size_t)row * NN + w16 * 16);
    unsigned m = 0;
    #pragma unroll
    for (int j = 0; j < 4; ++j) {
        int4 a = ap[j];
        m |= (a.x != 0 ? 1u : 0u) << (4*j);
        m |= (a.y != 0 ? 1u : 0u) << (4*j + 1);
        m |= (a.z != 0 ? 1u : 0u) << (4*j + 2);
        m |= (a.w != 0 ? 1u : 0u) << (4*j + 3);
    }
    if (w16 == (row >> 4)) m |= 1u << (row & 15);
    M16[(size_t)row * 256 + w16] = (unsigned short)m;
}

// ------------------------------------------------------------------
// Flash attention, split-K x4.
//  * compact u64 masks (2 MB, L2-resident) as round-0; halfword
//    AND-masks hm[8] generated via 16-entry LDS LUT:
//    nib = bfe(cm, 16*kt + 4*g, 4) -> ds_read_b64 LUT[nib].
//    LUT entries are 8B -> distinct nibbles hit disjoint bank pairs
//    (conflict-free), equal nibbles broadcast.
//  * masked row-max in packed fp16 (bfi to -inf + v_pk_max_f16 tree).
//  * mask applied post-exp as AND on packed fp16 P pairs; fp16-rounded
//    max cancels exactly in the split-K combine.
//  * l summed from the masked fp16 P words via v_pk_add_f16.
//  * LDS XOR-swizzle (byte ^= (row&7)<<4, 128B rows, no pads).
//  * s_setprio(1) around MFMA clusters.
// ------------------------------------------------------------------
__global__ __launch_bounds__(256) void gat_attn(
    const _Float16* __restrict__ qh, const _Float16* __restrict__ ql,
    const _Float16* __restrict__ kf16, const _Float16* __restrict__ vtb,
    const unsigned long long* __restrict__ M,
    _Float16* __restrict__ po, float2* __restrict__ pml)
{
    __shared__ alignas(16) _Float16 Kt[64][64];       // [key][c_in], swizzled
    __shared__ alignas(16) _Float16 Vt[64][64];       // [c_out][key], swizzled
    __shared__ alignas(16) _Float16 Ps[4][32][64];    // per-wave [qrow][key], swizzled
    __shared__ alignas(8) uint2 LUT[16];              // nib -> 2 halfword AND-masks
    const int t = threadIdx.x;
    const int lane = t & 63, wv = t >> 6;
    const int cl = lane & 15, g = lane >> 4;
    const int blk = blockIdx.x;        // 1024
    const int b  = blk & 7;            // batch == XCD (blk % 8 dispatch)
    const int sp = (blk >> 3) & 3;     // key split
    const int qb = blk >> 5;           // q tile 0..31
    const int Q0 = qb * 128 + wv * 32;
    const int c0 = sp * 16;            // first 64-key chunk of this split
    const int swz = (cl & 7) << 4;     // read-side XOR (row%8 == cl%8)

    if (t < 16) {
        unsigned n = t;
        LUT[n] = make_uint2(((n & 1u) ? 0x0000FFFFu : 0u) | ((n & 2u) ? 0xFFFF0000u : 0u),
                            ((n & 4u) ? 0x0000FFFFu : 0u) | ((n & 8u) ? 0xFFFF0000u : 0u));
    }

    // loop-invariant swizzled staging destinations (row = t>>3, +32)
    const int soff = (((t >> 3) * 128 + (t & 7) * 16) ^ (((t >> 3) & 7) << 4));
    char* const kd0 = (char*)Kt + soff;
    char* const kd1 = (char*)Kt + soff + 32 * 128;    // (row+32)&7 == row&7
    char* const vd0 = (char*)Vt + soff;
    char* const vd1 = (char*)Vt + soff + 32 * 128;
    char* const psb = (char*)&Ps[wv][0][0];

    half8 qfh[2][2], qfl[2][2];
    #pragma unroll
    for (int qt = 0; qt < 2; ++qt) {
        const _Float16* qrh = qh + ((size_t)b * NN + Q0 + qt*16 + cl) * CC;
        const _Float16* qrl = ql + ((size_t)b * NN + Q0 + qt*16 + cl) * CC;
        qfh[qt][0] = *(const half8*)(qrh + g*8);
        qfh[qt][1] = *(const half8*)(qrh + g*8 + 32);
        qfl[qt][0] = *(const half8*)(qrl + g*8);
        qfl[qt][1] = *(const half8*)(qrl + g*8 + 32);
    }
    const _Float16* kg = kf16 + (size_t)b * NN * CC;
    const _Float16* vg = vtb + (size_t)b * CC * NN;

    f32x4 o[2][4] = {};
    float m_run[2] = {MASKV, MASKV}, l_run[2] = {0.f, 0.f};

    uint4 pk0, pk1, pv0, pv1;
    unsigned long long pmA, pmB;
    auto loadchunk = [&](int kc) {                    // kc = global chunk id
        const uint4* ks = (const uint4*)(kg + (size_t)kc * 64 * CC);
        pk0 = ks[t];
        pk1 = ks[t + 256];
        const _Float16* vs = vg + kc * 64;
        pv0 = *(const uint4*)(vs + (size_t)(t >> 3) * NN + (t & 7) * 8);
        pv1 = *(const uint4*)(vs + (size_t)((t >> 3) + 32) * NN + (t & 7) * 8);
        pmA = M[(size_t)(Q0 + cl) * 64 + kc];
        pmB = M[(size_t)(Q0 + 16 + cl) * 64 + kc];
    };
    loadchunk(c0);

    auto pkmax = [](unsigned a, unsigned b) {
        unsigned d;
        asm("v_pk_max_f16 %0, %1, %2" : "=v"(d) : "v"(a), "v"(b));
        return d;
    };

    for (int kc = 0; kc < 16; ++kc) {
        __syncthreads();                 // previous tile's consumers done
        *(uint4*)kd0 = pk0;
        *(uint4*)kd1 = pk1;
        *(uint4*)vd0 = pv0;
        *(uint4*)vd1 = pv1;
        const unsigned long long cmA = pmA, cmB = pmB;
        __syncthreads();                 // tile ready
        if (kc < 15) loadchunk(c0 + kc + 1);   // overlap with compute

        // S^T tiles: D[key][qrow]; q hi/lo fp16 (K frag reused)
        __builtin_amdgcn_s_setprio(1);
        f32x4 sc[2][4] = {};
        #pragma unroll
        for (int kt = 0; kt < 4; ++kt) {
            #pragma unroll
            for (int kf = 0; kf < 2; ++kf) {
                half8 ka = *(const half8*)((char*)Kt +
                    ((((kt*16 + cl) * 128) + g*16 + kf*64) ^ swz));
                sc[0][kt] = __builtin_amdgcn_mfma_f32_16x16x32_f16(ka, qfh[0][kf], sc[0][kt], 0, 0, 0);
                sc[0][kt] = __builtin_amdgcn_mfma_f32_16x16x32_f16(ka, qfl[0][kf], sc[0][kt], 0, 0, 0);
                sc[1][kt] = __builtin_amdgcn_mfma_f32_16x16x32_f16(ka, qfh[1][kf], sc[1][kt], 0, 0, 0);
                sc[1][kt] = __builtin_amdgcn_mfma_f32_16x16x32_f16(ka, qfl[1][kf], sc[1][kt], 0, 0, 0);
            }
        }
        __builtin_amdgcn_s_setprio(0);

        // softmax (exp2 domain); lane owns q-row qt*16+cl.
        #pragma unroll
        for (int qt = 0; qt < 2; ++qt) {
            const unsigned long long cm = qt ? cmB : cmA;
            const unsigned wlo = (unsigned)cm, whi = (unsigned)(cm >> 32);
            // compact bits -> halfword AND masks via LDS LUT
            unsigned hm[8];
            #pragma unroll
            for (int kt = 0; kt < 4; ++kt) {
                unsigned w = (kt < 2) ? wlo : whi;
                unsigned nib = (w >> ((kt & 1) * 16 + 4 * g)) & 15u;
                uint2 e = LUT[nib];
                hm[2*kt]   = e.x;
                hm[2*kt+1] = e.y;
            }
            float sv[16];
            #pragma unroll
            for (int j = 0; j < 16; ++j) {
                float x = sc[qt][j >> 2][j & 3];
                sv[j] = fmaxf(x, 0.01f * x);          // leaky_relu
            }
            // masked row-max in packed fp16: (hm & s) | (~hm & -inf)
            union UH { unsigned u; fp16x2 h; };
            unsigned sm[8];
            #pragma unroll
            for (int kt = 0; kt < 4; ++kt) {
                UH s0, s1;
                s0.h = __builtin_amdgcn_cvt_pkrtz(sv[4*kt + 0], sv[4*kt + 1]);
                s1.h = __builtin_amdgcn_cvt_pkrtz(sv[4*kt + 2], sv[4*kt + 3]);
                sm[2*kt]   = (hm[2*kt]   & s0.u) | (~hm[2*kt]   & 0xFC00FC00u);
                sm[2*kt+1] = (hm[2*kt+1] & s1.u) | (~hm[2*kt+1] & 0xFC00FC00u);
            }
            unsigned tm = pkmax(
                pkmax(pkmax(sm[0], sm[1]), pkmax(sm[2], sm[3])),
                pkmax(pkmax(sm[4], sm[5]), pkmax(sm[6], sm[7])));
            UH tmu; tmu.u = tm;
            float mx = fmaxf((float)tmu.h[0], (float)tmu.h[1]);
            mx = fmaxf(mx, __shfl_xor(mx, 16));
            mx = fmaxf(mx, __shfl_xor(mx, 32));
            if (__any(mx > m_run[qt])) {                   // wave-uniform skip
                float nm = fmaxf(m_run[qt], mx);
                float alpha = __builtin_amdgcn_exp2f(m_run[qt] - nm);
                m_run[qt] = nm;
                l_run[qt] *= alpha;
                #pragma unroll
                for (int ct = 0; ct < 4; ++ct) o[qt][ct] *= alpha;
            }
            float p[16];
            #pragma unroll
            for (int j = 0; j < 16; ++j)
                p[j] = __builtin_amdgcn_exp2f(sv[j] - m_run[qt]);
            UH zz; zz.u = 0u;
            fp16x2 acc2 = zz.h;
            #pragma unroll
            for (int kt = 0; kt < 4; ++kt) {
                UH w0, w1;
                w0.h = __builtin_amdgcn_cvt_pkrtz(p[kt*4 + 0], p[kt*4 + 1]);
                w1.h = __builtin_amdgcn_cvt_pkrtz(p[kt*4 + 2], p[kt*4 + 3]);
                w0.u &= hm[2*kt];                      // masked -> 0
                w1.u &= hm[2*kt+1];
                uint2 pw = {w0.u, w1.u};
                *(uint2*)(psb + ((((qt*16 + cl) * 128) + kt*32 + g*8) ^ swz)) = pw;
                acc2 += w0.h + w1.h;                   // v_pk_add_f16 tree
            }
            l_run[qt] += (float)acc2[0] + (float)acc2[1];
        }
        __builtin_amdgcn_wave_barrier();   // same-wave DS in-order; fence scheduler

        half8 pf[2][2];
        #pragma unroll
        for (int qt = 0; qt < 2; ++qt) {
            pf[qt][0] = *(const half8*)(psb + ((((qt*16 + cl) * 128) + g*16) ^ swz));
            pf[qt][1] = *(const half8*)(psb + ((((qt*16 + cl) * 128) + g*16 + 64) ^ swz));
        }
        // O^T += V^T * P^T
        __builtin_amdgcn_s_setprio(1);
        #pragma unroll
        for (int ct = 0; ct < 4; ++ct) {
            half8 vf0 = *(const half8*)((char*)Vt + ((((ct*16 + cl) * 128) + g*16) ^ swz));
            half8 vf1 = *(const half8*)((char*)Vt + ((((ct*16 + cl) * 128) + g*16 + 64) ^ swz));
            #pragma unroll
            for (int qt = 0; qt < 2; ++qt) {
                o[qt][ct] = __builtin_amdgcn_mfma_f32_16x16x32_f16(vf0, pf[qt][0], o[qt][ct], 0, 0, 0);
                o[qt][ct] = __builtin_amdgcn_mfma_f32_16x16x32_f16(vf1, pf[qt][1], o[qt][ct], 0, 0, 0);
            }
        }
        __builtin_amdgcn_s_setprio(0);
    }

    // epilogue: store UNNORMALIZED fp16 partial o + (m, l) for combine
    #pragma unroll
    for (int qt = 0; qt < 2; ++qt) {
        float lt = l_run[qt];
        lt += __shfl_xor(lt, 16);
        lt += __shfl_xor(lt, 32);
        size_t base = (size_t)sp * (BATCH * NN) + (size_t)b * NN + Q0 + qt*16 + cl;
        _Float16* orow = po + base * 64;
        #pragma unroll
        for (int ct = 0; ct < 4; ++ct) {
            union { fp16x2 h; unsigned u; } o0u, o1u;
            o0u.h = __builtin_amdgcn_cvt_pkrtz(o[qt][ct][0], o[qt][ct][1]);
            o1u.h = __builtin_amdgcn_cvt_pkrtz(o[qt][ct][2], o[qt][ct][3]);
            uint2 ow = {o0u.u, o1u.u};
            *(uint2*)(orow + ct*16 + 4*g) = ow;
        }
        if (g == 0) pml[base] = make_float2(m_run[qt], lt);
    }
}

// ------------------------------------------------------------------
// Combine the 4 split-K partials: out = sum_s w_s*o_s / sum_s w_s*l_s,
// w_s = exp2(m_s - max_s m_s). Fully-masked splits have l=0, o=0.
// ------------------------------------------------------------------
__global__ __launch_bounds__(256) void gat_comb(
    const _Float16* __restrict__ po, const float2* __restrict__ pml,
    float* __restrict__ out)
{
    int gid = blockIdx.x * 256 + threadIdx.x;     // 131072 threads
    int row = gid >> 2;                            // 0..32767 (b*N + n)
    int col = (gid & 3) * 16;
    float2 ml[4];
    float Mx = MASKV;
    #pragma unroll
    for (int s = 0; s < 4; ++s) {
        ml[s] = pml[s * (BATCH * NN) + row];
        Mx = fmaxf(Mx, ml[s].x);
    }
    float w[4], den = 0.f;
    #pragma unroll
    for (int s = 0; s < 4; ++s) {
        w[s] = __builtin_amdgcn_exp2f(ml[s].x - Mx);
        den += w[s] * ml[s].y;
    }
    float inv = 1.0f / den;                        // diag guarantees den > 0
    float acc[16] = {};
    #pragma unroll
    for (int s = 0; s < 4; ++s) {
        const _Float16* p = po + ((size_t)s * (BATCH * NN) + row) * 64 + col;
        float a = w[s] * inv;
        half8 v0 = *(const half8*)(p);
        half8 v1 = *(const half8*)(p + 8);
        #pragma unroll
        for (int j = 0; j < 8; ++j) {
            acc[j]     += a * (float)v0[j];
            acc[j + 8] += a * (float)v1[j];
        }
    }
    float* op = out + (size_t)row * 64 + col;
    #pragma unroll
    for (int i = 0; i < 4; ++i) {
        f32x4 r = {acc[4*i], acc[4*i+1], acc[4*i+2], acc[4*i+3]};
        *(f32x4*)(op + i*4) = r;
    }
}

extern "C" void kernel_launch(void* const* d_in, const int* in_sizes, int n_in,
                              void* d_out, int out_size, void* d_ws, size_t ws_size,
                              hipStream_t stream) {
    const float* X  = (const float*)d_in[0];
    const int*   A  = (const int*)d_in[1];
    const float* W0 = (const float*)d_in[2];
    const float* Wq = (const float*)d_in[3];
    const float* Wk = (const float*)d_in[4];
    float* out = (float*)d_out;
    char* ws = (char*)d_ws;
    const size_t SZ = (size_t)BATCH * NN * CC * 2;        // 4 MB per fp16 tensor
    _Float16* qh  = (_Float16*)(ws);
    _Float16* ql  = (_Float16*)(ws + SZ);
    _Float16* kbf = (_Float16*)(ws + 2*SZ);
    _Float16* vtb = (_Float16*)(ws + 3*SZ);
    char* Mbase = ws + 4*SZ;                               // 2 MB mask
    _Float16* po = (_Float16*)(Mbase + 2*1024*1024);       // 16 MB (4 splits fp16)
    float2* pml  = (float2*)(Mbase + 2*1024*1024 + 4*SZ);  // 1 MB

    hipLaunchKernelGGL(gat_proj, dim3(512),  dim3(256), 0, stream, X, W0, Wq, Wk, qh, ql, kbf, vtb);
    hipLaunchKernelGGL(gat_mask, dim3(4096), dim3(256), 0, stream, A, (unsigned short*)Mbase);
    hipLaunchKernelGGL(gat_attn, dim3(1024), dim3(256), 0, stream, qh, ql, kbf, vtb,
                       (const unsigned long long*)Mbase, po, pml);
    hipLaunchKernelGGL(gat_comb, dim3(512),  dim3(256), 0, stream, po, pml, out);
}

// Round 4
// 203.583 us; speedup vs baseline: 1.0294x; 1.0103x over previous
//
#include <hip/hip_runtime.h>
#include <stdint.h>

#define BATCH 8
#define NN 4096
#define CC 64
#define MASKV -1.0e30f
#define LOG2E 1.4426950408889634f

typedef _Float16 half8 __attribute__((ext_vector_type(8)));
typedef __fp16 fp16x2 __attribute__((ext_vector_type(2)));
typedef float f32x4 __attribute__((ext_vector_type(4)));

// ------------------------------------------------------------------
// Projection: q (fp16, pre-scaled by log2e), k (fp16), vT (fp16,
// [b][c][n]). Split-compensated fp16 MFMA on the X/W inputs -> only
// fp16 STORAGE rounding (2^-11) survives. q-lo compensation DROPPED
// (round 4): k is plain fp16 anyway, so hi/lo q only halved one of two
// equal error terms at the cost of 16 MFMA/iter in attention.
// ------------------------------------------------------------------
__global__ __launch_bounds__(256) void gat_proj(
    const float* __restrict__ X, const float* __restrict__ W0,
    const float* __restrict__ Wq, const float* __restrict__ Wk,
    _Float16* __restrict__ qh,
    _Float16* __restrict__ kb, _Float16* __restrict__ vt)
{
    __shared__ alignas(16) _Float16 WTh[3][64][72];   // [mat][c_out][c_in], +8 pad
    __shared__ alignas(16) _Float16 WTl[3][64][72];
    const int t = threadIdx.x;
    const float* Ws[3] = {W0, Wq, Wk};
    for (int e = t; e < 4096; e += 256) {
        int k = e >> 6, c = e & 63;
        #pragma unroll
        for (int m = 0; m < 3; ++m) {
            float w = Ws[m][e];
            _Float16 hi = (_Float16)w;
            WTh[m][c][k] = hi;
            WTl[m][c][k] = (_Float16)(w - (float)hi);
        }
    }
    __syncthreads();
    const int lane = t & 63, wv = t >> 6;
    const int cl = lane & 15, g = lane >> 4;
    {
        int tile = blockIdx.x * 4 + wv;               // 2048 tiles of 16 rows
        int gr = tile * 16;
        const float* xr = X + (size_t)(gr + cl) * CC;
        half8 xh[2], xl[2];
        #pragma unroll
        for (int kf = 0; kf < 2; ++kf) {
            f32x4 a0 = *(const f32x4*)(xr + g*8 + kf*32);
            f32x4 a1 = *(const f32x4*)(xr + g*8 + kf*32 + 4);
            half8 h, l;
            #pragma unroll
            for (int j = 0; j < 4; ++j) {
                _Float16 h0 = (_Float16)a0[j], h1 = (_Float16)a1[j];
                h[j]   = h0; l[j]   = (_Float16)(a0[j] - (float)h0);
                h[j+4] = h1; l[j+4] = (_Float16)(a1[j] - (float)h1);
            }
            xh[kf] = h; xl[kf] = l;
        }
        // q and k: D[row][c_out] = X * W
        #pragma unroll
        for (int mat = 1; mat <= 2; ++mat) {
            #pragma unroll
            for (int nt = 0; nt < 4; ++nt) {
                f32x4 acc = {0.f, 0.f, 0.f, 0.f};
                #pragma unroll
                for (int kf = 0; kf < 2; ++kf) {
                    half8 bh = *(const half8*)&WTh[mat][nt*16 + cl][g*8 + kf*32];
                    half8 bl = *(const half8*)&WTl[mat][nt*16 + cl][g*8 + kf*32];
                    acc = __builtin_amdgcn_mfma_f32_16x16x32_f16(xh[kf], bh, acc, 0, 0, 0);
                    acc = __builtin_amdgcn_mfma_f32_16x16x32_f16(xl[kf], bh, acc, 0, 0, 0);
                    acc = __builtin_amdgcn_mfma_f32_16x16x32_f16(xh[kf], bl, acc, 0, 0, 0);
                }
                #pragma unroll
                for (int i = 0; i < 4; ++i) {
                    size_t off = (size_t)(gr + 4*g + i) * CC + nt*16 + cl;
                    if (mat == 1) {
                        qh[off] = (_Float16)(acc[i] * LOG2E);  // fold log2e
                    } else {
                        kb[off] = (_Float16)acc[i];
                    }
                }
            }
        }
        // vT: D[c_out][row] = W^T * X^T -> [b][c][n] layout
        {
            int b = gr >> 12, n0 = gr & (NN - 1);
            #pragma unroll
            for (int mt = 0; mt < 4; ++mt) {
                f32x4 acc = {0.f, 0.f, 0.f, 0.f};
                #pragma unroll
                for (int kf = 0; kf < 2; ++kf) {
                    half8 ah = *(const half8*)&WTh[0][mt*16 + cl][g*8 + kf*32];
                    half8 al = *(const half8*)&WTl[0][mt*16 + cl][g*8 + kf*32];
                    acc = __builtin_amdgcn_mfma_f32_16x16x32_f16(ah, xh[kf], acc, 0, 0, 0);
                    acc = __builtin_amdgcn_mfma_f32_16x16x32_f16(al, xh[kf], acc, 0, 0, 0);
                    acc = __builtin_amdgcn_mfma_f32_16x16x32_f16(ah, xl[kf], acc, 0, 0, 0);
                }
                #pragma unroll
                for (int i = 0; i < 4; ++i) {
                    int co = mt*16 + 4*g + i;
                    vt[((size_t)b * CC + co) * NN + n0 + cl] = (_Float16)acc[i];
                }
            }
        }
    }
}

// ------------------------------------------------------------------
// Adjacency -> bitmask (forced diagonal). Compact 2 MB stream,
// L2-resident per XCD.
// ------------------------------------------------------------------
__global__ __launch_bounds__(256) void gat_mask(const int* __restrict__ A,
                                                unsigned short* __restrict__ M16)
{
    const int row = blockIdx.x;
    const int w16 = threadIdx.x;
    const int4* ap = (const int4*)(A + (size_t)row * NN + w16 * 16);
    unsigned m = 0;
    #pragma unroll
    for (int j = 0; j < 4; ++j) {
        int4 a = ap[j];
        m |= (a.x != 0 ? 1u : 0u) << (4*j);
        m |= (a.y != 0 ? 1u : 0u) << (4*j + 1);
        m |= (a.z != 0 ? 1u : 0u) << (4*j + 2);
        m |= (a.w != 0 ? 1u : 0u) << (4*j + 3);
    }
    if (w16 == (row >> 4)) m |= 1u << (row & 15);
    M16[(size_t)row * 256 + w16] = (unsigned short)m;
}

// ------------------------------------------------------------------
// Flash attention, split-K x4.  Round-4 changes:
//  * single-fp16 q (16 QK MFMA/iter instead of 32): the kernel is
//    dependency-bound (3 softmax variants all timed 102us), so cut
//    matrix-pipe work and chain depth; k was plain fp16 anyway.
//  * per-qt interleave {softmax(qt); Ps write; pf/vf read; PV(qt)}:
//    PV(qt0)'s 8 MFMAs execute under softmax(qt1)'s serial chain
//    (pkmax tree -> 2 shfl -> exp) instead of bunching at the end.
//  * retained: LUT mask expand, packed-fp16 masked max, post-exp AND,
//    pk_add l-sum, XOR-swizzled LDS, setprio around MFMA clusters.
// ------------------------------------------------------------------
__global__ __launch_bounds__(256) void gat_attn(
    const _Float16* __restrict__ qg,
    const _Float16* __restrict__ kf16, const _Float16* __restrict__ vtb,
    const unsigned long long* __restrict__ M,
    _Float16* __restrict__ po, float2* __restrict__ pml)
{
    __shared__ alignas(16) _Float16 Kt[64][64];       // [key][c_in], swizzled
    __shared__ alignas(16) _Float16 Vt[64][64];       // [c_out][key], swizzled
    __shared__ alignas(16) _Float16 Ps[4][32][64];    // per-wave [qrow][key], swizzled
    __shared__ alignas(8) uint2 LUT[16];              // nib -> 2 halfword AND-masks
    const int t = threadIdx.x;
    const int lane = t & 63, wv = t >> 6;
    const int cl = lane & 15, g = lane >> 4;
    const int blk = blockIdx.x;        // 1024
    const int b  = blk & 7;            // batch == XCD (blk % 8 dispatch)
    const int sp = (blk >> 3) & 3;     // key split
    const int qb = blk >> 5;           // q tile 0..31
    const int Q0 = qb * 128 + wv * 32;
    const int c0 = sp * 16;            // first 64-key chunk of this split
    const int swz = (cl & 7) << 4;     // read-side XOR (row%8 == cl%8)

    if (t < 16) {
        unsigned n = t;
        LUT[n] = make_uint2(((n & 1u) ? 0x0000FFFFu : 0u) | ((n & 2u) ? 0xFFFF0000u : 0u),
                            ((n & 4u) ? 0x0000FFFFu : 0u) | ((n & 8u) ? 0xFFFF0000u : 0u));
    }

    // loop-invariant swizzled staging destinations (row = t>>3, +32)
    const int soff = (((t >> 3) * 128 + (t & 7) * 16) ^ (((t >> 3) & 7) << 4));
    char* const kd0 = (char*)Kt + soff;
    char* const kd1 = (char*)Kt + soff + 32 * 128;    // (row+32)&7 == row&7
    char* const vd0 = (char*)Vt + soff;
    char* const vd1 = (char*)Vt + soff + 32 * 128;
    char* const psb = (char*)&Ps[wv][0][0];

    half8 qf[2][2];
    #pragma unroll
    for (int qt = 0; qt < 2; ++qt) {
        const _Float16* qr = qg + ((size_t)b * NN + Q0 + qt*16 + cl) * CC;
        qf[qt][0] = *(const half8*)(qr + g*8);
        qf[qt][1] = *(const half8*)(qr + g*8 + 32);
    }
    const _Float16* kg = kf16 + (size_t)b * NN * CC;
    const _Float16* vg = vtb + (size_t)b * CC * NN;

    f32x4 o[2][4] = {};
    float m_run[2] = {MASKV, MASKV}, l_run[2] = {0.f, 0.f};

    uint4 pk0, pk1, pv0, pv1;
    unsigned long long pmA, pmB;
    auto loadchunk = [&](int kc) {                    // kc = global chunk id
        const uint4* ks = (const uint4*)(kg + (size_t)kc * 64 * CC);
        pk0 = ks[t];
        pk1 = ks[t + 256];
        const _Float16* vs = vg + kc * 64;
        pv0 = *(const uint4*)(vs + (size_t)(t >> 3) * NN + (t & 7) * 8);
        pv1 = *(const uint4*)(vs + (size_t)((t >> 3) + 32) * NN + (t & 7) * 8);
        pmA = M[(size_t)(Q0 + cl) * 64 + kc];
        pmB = M[(size_t)(Q0 + 16 + cl) * 64 + kc];
    };
    loadchunk(c0);

    auto pkmax = [](unsigned a, unsigned b) {
        unsigned d;
        asm("v_pk_max_f16 %0, %1, %2" : "=v"(d) : "v"(a), "v"(b));
        return d;
    };

    for (int kc = 0; kc < 16; ++kc) {
        __syncthreads();                 // previous tile's consumers done
        *(uint4*)kd0 = pk0;
        *(uint4*)kd1 = pk1;
        *(uint4*)vd0 = pv0;
        *(uint4*)vd1 = pv1;
        const unsigned long long cmA = pmA, cmB = pmB;
        __syncthreads();                 // tile ready
        if (kc < 15) loadchunk(c0 + kc + 1);   // overlap with compute

        // S^T tiles: D[key][qrow]
        __builtin_amdgcn_s_setprio(1);
        f32x4 sc[2][4] = {};
        #pragma unroll
        for (int kt = 0; kt < 4; ++kt) {
            #pragma unroll
            for (int kf = 0; kf < 2; ++kf) {
                half8 ka = *(const half8*)((char*)Kt +
                    ((((kt*16 + cl) * 128) + g*16 + kf*64) ^ swz));
                sc[0][kt] = __builtin_amdgcn_mfma_f32_16x16x32_f16(ka, qf[0][kf], sc[0][kt], 0, 0, 0);
                sc[1][kt] = __builtin_amdgcn_mfma_f32_16x16x32_f16(ka, qf[1][kf], sc[1][kt], 0, 0, 0);
            }
        }
        __builtin_amdgcn_s_setprio(0);

        // per-qt: softmax then PV(qt) -- PV(qt0) MFMAs overlap
        // softmax(qt1)'s serial VALU chain.
        #pragma unroll
        for (int qt = 0; qt < 2; ++qt) {
            const unsigned long long cm = qt ? cmB : cmA;
            const unsigned wlo = (unsigned)cm, whi = (unsigned)(cm >> 32);
            // compact bits -> halfword AND masks via LDS LUT
            unsigned hm[8];
            #pragma unroll
            for (int kt = 0; kt < 4; ++kt) {
                unsigned w = (kt < 2) ? wlo : whi;
                unsigned nib = (w >> ((kt & 1) * 16 + 4 * g)) & 15u;
                uint2 e = LUT[nib];
                hm[2*kt]   = e.x;
                hm[2*kt+1] = e.y;
            }
            float sv[16];
            #pragma unroll
            for (int j = 0; j < 16; ++j) {
                float x = sc[qt][j >> 2][j & 3];
                sv[j] = fmaxf(x, 0.01f * x);          // leaky_relu
            }
            // masked row-max in packed fp16: (hm & s) | (~hm & -inf)
            union UH { unsigned u; fp16x2 h; };
            unsigned sm[8];
            #pragma unroll
            for (int kt = 0; kt < 4; ++kt) {
                UH s0, s1;
                s0.h = __builtin_amdgcn_cvt_pkrtz(sv[4*kt + 0], sv[4*kt + 1]);
                s1.h = __builtin_amdgcn_cvt_pkrtz(sv[4*kt + 2], sv[4*kt + 3]);
                sm[2*kt]   = (hm[2*kt]   & s0.u) | (~hm[2*kt]   & 0xFC00FC00u);
                sm[2*kt+1] = (hm[2*kt+1] & s1.u) | (~hm[2*kt+1] & 0xFC00FC00u);
            }
            unsigned tm = pkmax(
                pkmax(pkmax(sm[0], sm[1]), pkmax(sm[2], sm[3])),
                pkmax(pkmax(sm[4], sm[5]), pkmax(sm[6], sm[7])));
            UH tmu; tmu.u = tm;
            float mx = fmaxf((float)tmu.h[0], (float)tmu.h[1]);
            mx = fmaxf(mx, __shfl_xor(mx, 16));
            mx = fmaxf(mx, __shfl_xor(mx, 32));
            if (__any(mx > m_run[qt])) {                   // wave-uniform skip
                float nm = fmaxf(m_run[qt], mx);
                float alpha = __builtin_amdgcn_exp2f(m_run[qt] - nm);
                m_run[qt] = nm;
                l_run[qt] *= alpha;
                #pragma unroll
                for (int ct = 0; ct < 4; ++ct) o[qt][ct] *= alpha;
            }
            float p[16];
            #pragma unroll
            for (int j = 0; j < 16; ++j)
                p[j] = __builtin_amdgcn_exp2f(sv[j] - m_run[qt]);
            UH zz; zz.u = 0u;
            fp16x2 acc2 = zz.h;
            #pragma unroll
            for (int kt = 0; kt < 4; ++kt) {
                UH w0, w1;
                w0.h = __builtin_amdgcn_cvt_pkrtz(p[kt*4 + 0], p[kt*4 + 1]);
                w1.h = __builtin_amdgcn_cvt_pkrtz(p[kt*4 + 2], p[kt*4 + 3]);
                w0.u &= hm[2*kt];                      // masked -> 0
                w1.u &= hm[2*kt+1];
                uint2 pw = {w0.u, w1.u};
                *(uint2*)(psb + ((((qt*16 + cl) * 128) + kt*32 + g*8) ^ swz)) = pw;
                acc2 += w0.h + w1.h;                   // v_pk_add_f16 tree
            }
            l_run[qt] += (float)acc2[0] + (float)acc2[1];

            __builtin_amdgcn_wave_barrier();   // same-wave DS in-order; fence scheduler

            half8 pf0 = *(const half8*)(psb + ((((qt*16 + cl) * 128) + g*16) ^ swz));
            half8 pf1 = *(const half8*)(psb + ((((qt*16 + cl) * 128) + g*16 + 64) ^ swz));
            // O^T[qt] += V^T * P^T[qt]
            __builtin_amdgcn_s_setprio(1);
            #pragma unroll
            for (int ct = 0; ct < 4; ++ct) {
                half8 vf0 = *(const half8*)((char*)Vt + ((((ct*16 + cl) * 128) + g*16) ^ swz));
                half8 vf1 = *(const half8*)((char*)Vt + ((((ct*16 + cl) * 128) + g*16 + 64) ^ swz));
                o[qt][ct] = __builtin_amdgcn_mfma_f32_16x16x32_f16(vf0, pf0, o[qt][ct], 0, 0, 0);
                o[qt][ct] = __builtin_amdgcn_mfma_f32_16x16x32_f16(vf1, pf1, o[qt][ct], 0, 0, 0);
            }
            __builtin_amdgcn_s_setprio(0);
        }
    }

    // epilogue: store UNNORMALIZED fp16 partial o + (m, l) for combine
    #pragma unroll
    for (int qt = 0; qt < 2; ++qt) {
        float lt = l_run[qt];
        lt += __shfl_xor(lt, 16);
        lt += __shfl_xor(lt, 32);
        size_t base = (size_t)sp * (BATCH * NN) + (size_t)b * NN + Q0 + qt*16 + cl;
        _Float16* orow = po + base * 64;
        #pragma unroll
        for (int ct = 0; ct < 4; ++ct) {
            union { fp16x2 h; unsigned u; } o0u, o1u;
            o0u.h = __builtin_amdgcn_cvt_pkrtz(o[qt][ct][0], o[qt][ct][1]);
            o1u.h = __builtin_amdgcn_cvt_pkrtz(o[qt][ct][2], o[qt][ct][3]);
            uint2 ow = {o0u.u, o1u.u};
            *(uint2*)(orow + ct*16 + 4*g) = ow;
        }
        if (g == 0) pml[base] = make_float2(m_run[qt], lt);
    }
}

// ------------------------------------------------------------------
// Combine the 4 split-K partials: out = sum_s w_s*o_s / sum_s w_s*l_s,
// w_s = exp2(m_s - max_s m_s). Fully-masked splits have l=0, o=0.
// ------------------------------------------------------------------
__global__ __launch_bounds__(256) void gat_comb(
    const _Float16* __restrict__ po, const float2* __restrict__ pml,
    float* __restrict__ out)
{
    int gid = blockIdx.x * 256 + threadIdx.x;     // 131072 threads
    int row = gid >> 2;                            // 0..32767 (b*N + n)
    int col = (gid & 3) * 16;
    float2 ml[4];
    float Mx = MASKV;
    #pragma unroll
    for (int s = 0; s < 4; ++s) {
        ml[s] = pml[s * (BATCH * NN) + row];
        Mx = fmaxf(Mx, ml[s].x);
    }
    float w[4], den = 0.f;
    #pragma unroll
    for (int s = 0; s < 4; ++s) {
        w[s] = __builtin_amdgcn_exp2f(ml[s].x - Mx);
        den += w[s] * ml[s].y;
    }
    float inv = 1.0f / den;                        // diag guarantees den > 0
    float acc[16] = {};
    #pragma unroll
    for (int s = 0; s < 4; ++s) {
        const _Float16* p = po + ((size_t)s * (BATCH * NN) + row) * 64 + col;
        float a = w[s] * inv;
        half8 v0 = *(const half8*)(p);
        half8 v1 = *(const half8*)(p + 8);
        #pragma unroll
        for (int j = 0; j < 8; ++j) {
            acc[j]     += a * (float)v0[j];
            acc[j + 8] += a * (float)v1[j];
        }
    }
    float* op = out + (size_t)row * 64 + col;
    #pragma unroll
    for (int i = 0; i < 4; ++i) {
        f32x4 r = {acc[4*i], acc[4*i+1], acc[4*i+2], acc[4*i+3]};
        *(f32x4*)(op + i*4) = r;
    }
}

extern "C" void kernel_launch(void* const* d_in, const int* in_sizes, int n_in,
                              void* d_out, int out_size, void* d_ws, size_t ws_size,
                              hipStream_t stream) {
    const float* X  = (const float*)d_in[0];
    const int*   A  = (const int*)d_in[1];
    const float* W0 = (const float*)d_in[2];
    const float* Wq = (const float*)d_in[3];
    const float* Wk = (const float*)d_in[4];
    float* out = (float*)d_out;
    char* ws = (char*)d_ws;
    const size_t SZ = (size_t)BATCH * NN * CC * 2;        // 4 MB per fp16 tensor
    _Float16* qh  = (_Float16*)(ws);
    _Float16* kbf = (_Float16*)(ws + SZ);
    _Float16* vtb = (_Float16*)(ws + 2*SZ);
    char* Mbase = ws + 3*SZ;                               // 2 MB mask
    _Float16* po = (_Float16*)(Mbase + 2*1024*1024);       // 16 MB (4 splits fp16)
    float2* pml  = (float2*)(Mbase + 2*1024*1024 + 4*SZ);  // 1 MB

    hipLaunchKernelGGL(gat_proj, dim3(512),  dim3(256), 0, stream, X, W0, Wq, Wk, qh, kbf, vtb);
    hipLaunchKernelGGL(gat_mask, dim3(4096), dim3(256), 0, stream, A, (unsigned short*)Mbase);
    hipLaunchKernelGGL(gat_attn, dim3(1024), dim3(256), 0, stream, qh, kbf, vtb,
                       (const unsigned long long*)Mbase, po, pml);
    hipLaunchKernelGGL(gat_comb, dim3(512),  dim3(256), 0, stream, po, pml, out);
}

// Round 6
// 199.195 us; speedup vs baseline: 1.0521x; 1.0220x over previous
//
#include <hip/hip_runtime.h>
#include <stdint.h>

#define BATCH 8
#define NN 4096
#define CC 64
#define MASKV -1.0e30f
#define LOG2E 1.4426950408889634f

typedef _Float16 half8 __attribute__((ext_vector_type(8)));
typedef __fp16 fp16x2 __attribute__((ext_vector_type(2)));
typedef float f32x4 __attribute__((ext_vector_type(4)));
typedef float f32x16 __attribute__((ext_vector_type(16)));

__device__ __forceinline__ unsigned pk_rtz(float a, float b) {
    union { fp16x2 h; unsigned u; } r;
    r.h = __builtin_amdgcn_cvt_pkrtz(a, b);
    return r.u;
}

// ------------------------------------------------------------------
// Projection: q (fp16, pre-scaled by log2e), k (fp16), vT (fp16,
// [b][c][n]). Split-compensated fp16 MFMA on X/W inputs. (unchanged)
// ------------------------------------------------------------------
__global__ __launch_bounds__(256) void gat_proj(
    const float* __restrict__ X, const float* __restrict__ W0,
    const float* __restrict__ Wq, const float* __restrict__ Wk,
    _Float16* __restrict__ qh,
    _Float16* __restrict__ kb, _Float16* __restrict__ vt)
{
    __shared__ alignas(16) _Float16 WTh[3][64][72];
    __shared__ alignas(16) _Float16 WTl[3][64][72];
    const int t = threadIdx.x;
    const float* Ws[3] = {W0, Wq, Wk};
    for (int e = t; e < 4096; e += 256) {
        int k = e >> 6, c = e & 63;
        #pragma unroll
        for (int m = 0; m < 3; ++m) {
            float w = Ws[m][e];
            _Float16 hi = (_Float16)w;
            WTh[m][c][k] = hi;
            WTl[m][c][k] = (_Float16)(w - (float)hi);
        }
    }
    __syncthreads();
    const int lane = t & 63, wv = t >> 6;
    const int cl = lane & 15, g = lane >> 4;
    {
        int tile = blockIdx.x * 4 + wv;
        int gr = tile * 16;
        const float* xr = X + (size_t)(gr + cl) * CC;
        half8 xh[2], xl[2];
        #pragma unroll
        for (int kf = 0; kf < 2; ++kf) {
            f32x4 a0 = *(const f32x4*)(xr + g*8 + kf*32);
            f32x4 a1 = *(const f32x4*)(xr + g*8 + kf*32 + 4);
            half8 h, l;
            #pragma unroll
            for (int j = 0; j < 4; ++j) {
                _Float16 h0 = (_Float16)a0[j], h1 = (_Float16)a1[j];
                h[j]   = h0; l[j]   = (_Float16)(a0[j] - (float)h0);
                h[j+4] = h1; l[j+4] = (_Float16)(a1[j] - (float)h1);
            }
            xh[kf] = h; xl[kf] = l;
        }
        #pragma unroll
        for (int mat = 1; mat <= 2; ++mat) {
            #pragma unroll
            for (int nt = 0; nt < 4; ++nt) {
                f32x4 acc = {0.f, 0.f, 0.f, 0.f};
                #pragma unroll
                for (int kf = 0; kf < 2; ++kf) {
                    half8 bh = *(const half8*)&WTh[mat][nt*16 + cl][g*8 + kf*32];
                    half8 bl = *(const half8*)&WTl[mat][nt*16 + cl][g*8 + kf*32];
                    acc = __builtin_amdgcn_mfma_f32_16x16x32_f16(xh[kf], bh, acc, 0, 0, 0);
                    acc = __builtin_amdgcn_mfma_f32_16x16x32_f16(xl[kf], bh, acc, 0, 0, 0);
                    acc = __builtin_amdgcn_mfma_f32_16x16x32_f16(xh[kf], bl, acc, 0, 0, 0);
                }
                #pragma unroll
                for (int i = 0; i < 4; ++i) {
                    size_t off = (size_t)(gr + 4*g + i) * CC + nt*16 + cl;
                    if (mat == 1) qh[off] = (_Float16)(acc[i] * LOG2E);
                    else          kb[off] = (_Float16)acc[i];
                }
            }
        }
        {
            int b = gr >> 12, n0 = gr & (NN - 1);
            #pragma unroll
            for (int mt = 0; mt < 4; ++mt) {
                f32x4 acc = {0.f, 0.f, 0.f, 0.f};
                #pragma unroll
                for (int kf = 0; kf < 2; ++kf) {
                    half8 ah = *(const half8*)&WTh[0][mt*16 + cl][g*8 + kf*32];
                    half8 al = *(const half8*)&WTl[0][mt*16 + cl][g*8 + kf*32];
                    acc = __builtin_amdgcn_mfma_f32_16x16x32_f16(ah, xh[kf], acc, 0, 0, 0);
                    acc = __builtin_amdgcn_mfma_f32_16x16x32_f16(al, xh[kf], acc, 0, 0, 0);
                    acc = __builtin_amdgcn_mfma_f32_16x16x32_f16(ah, xl[kf], acc, 0, 0, 0);
                }
                #pragma unroll
                for (int i = 0; i < 4; ++i) {
                    int co = mt*16 + 4*g + i;
                    vt[((size_t)b * CC + co) * NN + n0 + cl] = (_Float16)acc[i];
                }
            }
        }
    }
}

// ------------------------------------------------------------------
// Adjacency -> bitmask (forced diagonal). Compact 2 MB, L2-resident.
// ------------------------------------------------------------------
__global__ __launch_bounds__(256) void gat_mask(const int* __restrict__ A,
                                                unsigned short* __restrict__ M16)
{
    const int row = blockIdx.x;
    const int w16 = threadIdx.x;
    const int4* ap = (const int4*)(A + (size_t)row * NN + w16 * 16);
    unsigned m = 0;
    #pragma unroll
    for (int j = 0; j < 4; ++j) {
        int4 a = ap[j];
        m |= (a.x != 0 ? 1u : 0u) << (4*j);
        m |= (a.y != 0 ? 1u : 0u) << (4*j + 1);
        m |= (a.z != 0 ? 1u : 0u) << (4*j + 2);
        m |= (a.w != 0 ? 1u : 0u) << (4*j + 3);
    }
    if (w16 == (row >> 4)) m |= 1u << (row & 15);
    M16[(size_t)row * 256 + w16] = (unsigned short)m;
}

// ------------------------------------------------------------------
// Flash attention, split-K x4 -- 32x32 structure (round 6):
//  * 32x32x16 MFMA; each lane owns one q-row, 32 of 64 keys (the
//    other 32 live in the partner lane = lane^32).
//  * cross-half exchange via __shfl_xor(.,32) ONLY (direction-proof;
//    round-5's v_permlane32_swap bet on an unverifiable half-exchange
//    convention and scrambled P->V pairing).
//  * P redistributed to B-frag layout in registers: per 4-word group,
//    u = hi?w0:w2; su=shfl_xor(u,32); slot0=hi?su:w0; slot2=hi?w2:su
//    (same for w1/w3) -- 8 bpermutes/iter, all independent.
//  * K/V double-buffered in LDS -> ONE __syncthreads per iteration.
//  * stabilizer m = max(0, masked raw max) (leaky scores bounded
//    below by ~-1.5, so the gap never matters; masked entries AND to
//    +0 pre-max, P words AND to 0 post-exp).
// ------------------------------------------------------------------
__global__ __launch_bounds__(256) void gat_attn(
    const _Float16* __restrict__ qg,
    const _Float16* __restrict__ kf16, const _Float16* __restrict__ vtb,
    const unsigned long long* __restrict__ M,
    _Float16* __restrict__ po, float2* __restrict__ pml)
{
    __shared__ alignas(16) _Float16 Kt[2][64][64];    // [buf][key][c_in], swizzled
    __shared__ alignas(16) _Float16 Vt[2][64][64];    // [buf][c_out][key], swizzled
    __shared__ alignas(8) uint2 LUT[16];              // nib -> 2 halfword AND-masks
    const int t = threadIdx.x;
    const int lane = t & 63, wv = t >> 6;
    const int q32 = lane & 31, hi = lane >> 5;
    const int blk = blockIdx.x;        // 1024
    const int b  = blk & 7;            // batch == XCD
    const int sp = (blk >> 3) & 3;     // key split
    const int qb = blk >> 5;           // q tile 0..31
    const int Q0 = qb * 128 + wv * 32;
    const int c0 = sp * 16;
    const int swz = (q32 & 7) << 4;    // read-side XOR (row%8)

    if (t < 16) {
        unsigned n = t;
        LUT[n] = make_uint2(((n & 1u) ? 0x0000FFFFu : 0u) | ((n & 2u) ? 0xFFFF0000u : 0u),
                            ((n & 4u) ? 0x0000FFFFu : 0u) | ((n & 8u) ? 0xFFFF0000u : 0u));
    }

    const int soff = (((t >> 3) * 128 + (t & 7) * 16) ^ (((t >> 3) & 7) << 4));

    half8 qf[4];                                       // B-frag: c = kf*16 + hi*8 + j
    {
        const _Float16* qr = qg + ((size_t)b * NN + Q0 + q32) * CC + hi * 8;
        #pragma unroll
        for (int kf = 0; kf < 4; ++kf) qf[kf] = *(const half8*)(qr + kf * 16);
    }
    const _Float16* kg = kf16 + (size_t)b * NN * CC;
    const _Float16* vg = vtb + (size_t)b * CC * NN;

    f32x16 o0 = {}, o1 = {};
    float m_run = 0.f, l_run = 0.f;

    uint4 pk0, pk1, pv0, pv1;
    unsigned long long pm;
    auto loadchunk = [&](int kcg) {
        const uint4* ks = (const uint4*)(kg + (size_t)kcg * 64 * CC);
        pk0 = ks[t];
        pk1 = ks[t + 256];
        const _Float16* vs = vg + kcg * 64;
        pv0 = *(const uint4*)(vs + (size_t)(t >> 3) * NN + (t & 7) * 8);
        pv1 = *(const uint4*)(vs + (size_t)((t >> 3) + 32) * NN + (t & 7) * 8);
        pm  = M[(size_t)(Q0 + q32) * 64 + kcg];
    };
    auto stash = [&](int bufi) {
        char* kd = (char*)&Kt[bufi][0][0];
        char* vd = (char*)&Vt[bufi][0][0];
        *(uint4*)(kd + soff) = pk0;
        *(uint4*)(kd + soff + 4096) = pk1;
        *(uint4*)(vd + soff) = pv0;
        *(uint4*)(vd + soff + 4096) = pv1;
    };
    auto pkmax = [](unsigned a, unsigned b) {
        unsigned d;
        asm("v_pk_max_f16 %0, %1, %2" : "=v"(d) : "v"(a), "v"(b));
        return d;
    };

    loadchunk(c0);
    unsigned long long cm = pm;
    stash(0);
    __syncthreads();

    for (int kc = 0; kc < 16; ++kc) {
        const int cur = kc & 1;
        if (kc < 15) loadchunk(c0 + kc + 1);   // issue early; consumed mid-iter

        // ---- QK: S^T[key][qrow], 2 key-blocks x 4 k-chunks
        const char* kbase = (const char*)&Kt[cur][0][0] + q32 * 128;
        __builtin_amdgcn_s_setprio(1);
        f32x16 s0 = {}, s1 = {};
        #pragma unroll
        for (int kf = 0; kf < 4; ++kf) {
            const int col = (kf * 32 + hi * 16) ^ swz;
            half8 ka0 = *(const half8*)(kbase + col);
            half8 ka1 = *(const half8*)(kbase + 4096 + col);
            s0 = __builtin_amdgcn_mfma_f32_32x32x16_f16(ka0, qf[kf], s0, 0, 0, 0);
            s1 = __builtin_amdgcn_mfma_f32_32x32x16_f16(ka1, qf[kf], s1, 0, 0, 0);
        }
        __builtin_amdgcn_s_setprio(0);

        // ---- halfword AND masks (sc order): 8 nibbles via LUT
        const unsigned wlo = (unsigned)cm, whi = (unsigned)(cm >> 32);
        unsigned hm[16];
        #pragma unroll
        for (int kt = 0; kt < 2; ++kt) {
            unsigned w = kt ? whi : wlo;
            #pragma unroll
            for (int a = 0; a < 4; ++a) {
                unsigned nib = (w >> (8 * a + 4 * hi)) & 15u;
                uint2 e = LUT[nib];
                hm[kt*8 + 2*a]     = e.x;
                hm[kt*8 + 2*a + 1] = e.y;
            }
        }
        // ---- masked raw-score max (packed fp16), clamp 0
        {
            unsigned sm[16];
            #pragma unroll
            for (int j = 0; j < 8; ++j) {
                sm[j]   = pk_rtz(s0[2*j], s0[2*j+1]) & hm[j];
                sm[8+j] = pk_rtz(s1[2*j], s1[2*j+1]) & hm[8+j];
            }
            unsigned u0 = pkmax(pkmax(pkmax(sm[0],sm[1]),  pkmax(sm[2],sm[3])),
                                pkmax(pkmax(sm[4],sm[5]),  pkmax(sm[6],sm[7])));
            unsigned u1 = pkmax(pkmax(pkmax(sm[8],sm[9]),  pkmax(sm[10],sm[11])),
                                pkmax(pkmax(sm[12],sm[13]),pkmax(sm[14],sm[15])));
            union { unsigned u; fp16x2 h; } tu; tu.u = pkmax(u0, u1);
            float mx = fmaxf(fmaxf((float)tu.h[0], (float)tu.h[1]), 0.f);
            mx = fmaxf(mx, __shfl_xor(mx, 32));        // partner half (direction-proof)
            if (__any(mx > m_run)) {                   // wave-uniform skip
                float nm = fmaxf(m_run, mx);
                float alpha = __builtin_amdgcn_exp2f(m_run - nm);
                m_run = nm;
                l_run *= alpha;
                #pragma unroll
                for (int i = 0; i < 16; ++i) { o0[i] *= alpha; o1[i] *= alpha; }
            }
        }
        // ---- p = exp2(leaky(s) - m), pack + mask (sc order)
        unsigned wp[16];
        #pragma unroll
        for (int j = 0; j < 8; ++j) {
            float p0 = __builtin_amdgcn_exp2f(fmaxf(s0[2*j]   - m_run, fmaf(0.01f, s0[2*j],   -m_run)));
            float p1 = __builtin_amdgcn_exp2f(fmaxf(s0[2*j+1] - m_run, fmaf(0.01f, s0[2*j+1], -m_run)));
            float p2 = __builtin_amdgcn_exp2f(fmaxf(s1[2*j]   - m_run, fmaf(0.01f, s1[2*j],   -m_run)));
            float p3 = __builtin_amdgcn_exp2f(fmaxf(s1[2*j+1] - m_run, fmaf(0.01f, s1[2*j+1], -m_run)));
            wp[j]   = pk_rtz(p0, p1) & hm[j];
            wp[8+j] = pk_rtz(p2, p3) & hm[8+j];
        }
        // ---- l sum over own half (packed); pair-sum deferred to epilogue
        {
            union { unsigned u; fp16x2 h; } z; z.u = 0u;
            fp16x2 acc = z.h;
            #pragma unroll
            for (int j4 = 0; j4 < 4; ++j4) {
                union { unsigned u; fp16x2 h; } x0, x1, x2, x3;
                x0.u = wp[4*j4]; x1.u = wp[4*j4+1]; x2.u = wp[4*j4+2]; x3.u = wp[4*j4+3];
                acc += (x0.h + x1.h) + (x2.h + x3.h);
            }
            l_run += (float)acc[0] + (float)acc[1];
        }
        // ---- stage next tile (loads have had QK+softmax to land)
        if (kc < 15) stash(cur ^ 1);
        // ---- redistribute P -> B-frag layout via shfl_xor(32):
        // per group g4 (16 keys): own words w0..w3 hold keys
        // {4hi+0,1},{4hi+2,3},{8+4hi+0,1},{8+4hi+2,3}; needed slots are
        // keys hi*8+{0..7}. One shfl serves two slots.
        #pragma unroll
        for (int g4 = 0; g4 < 4; ++g4) {
            unsigned w0 = wp[4*g4+0], w1 = wp[4*g4+1];
            unsigned w2 = wp[4*g4+2], w3 = wp[4*g4+3];
            unsigned u = hi ? w0 : w2;
            unsigned v = hi ? w1 : w3;
            unsigned su = (unsigned)__shfl_xor((int)u, 32);
            unsigned sv = (unsigned)__shfl_xor((int)v, 32);
            wp[4*g4+0] = hi ? su : w0;
            wp[4*g4+1] = hi ? sv : w1;
            wp[4*g4+2] = hi ? w2 : su;
            wp[4*g4+3] = hi ? w3 : sv;
        }
        // ---- PV: O^T += V^T * P^T
        const char* vb = (const char*)&Vt[cur][0][0] + q32 * 128;
        __builtin_amdgcn_s_setprio(1);
        #pragma unroll
        for (int kc4 = 0; kc4 < 4; ++kc4) {
            union { unsigned u[4]; half8 h; } pb;
            pb.u[0] = wp[4*kc4+0]; pb.u[1] = wp[4*kc4+1];
            pb.u[2] = wp[4*kc4+2]; pb.u[3] = wp[4*kc4+3];
            const int col = (kc4 * 32 + hi * 16) ^ swz;
            half8 vf0 = *(const half8*)(vb + col);
            half8 vf1 = *(const half8*)(vb + 4096 + col);
            o0 = __builtin_amdgcn_mfma_f32_32x32x16_f16(vf0, pb.h, o0, 0, 0, 0);
            o1 = __builtin_amdgcn_mfma_f32_32x32x16_f16(vf1, pb.h, o1, 0, 0, 0);
        }
        __builtin_amdgcn_s_setprio(0);
        cm = pm;
        if (kc < 15) __syncthreads();
    }

    // epilogue: unnormalized fp16 partial o + (m, l) for combine
    float lt = l_run + __shfl_xor(l_run, 32);
    size_t base = (size_t)sp * (BATCH * NN) + (size_t)b * NN + Q0 + q32;
    _Float16* orow = po + base * 64;
    #pragma unroll
    for (int a = 0; a < 4; ++a) {
        {
            uint2 ow = { pk_rtz(o0[4*a], o0[4*a+1]), pk_rtz(o0[4*a+2], o0[4*a+3]) };
            *(uint2*)(orow + 8*a + 4*hi) = ow;
        }
        {
            uint2 ow = { pk_rtz(o1[4*a], o1[4*a+1]), pk_rtz(o1[4*a+2], o1[4*a+3]) };
            *(uint2*)(orow + 32 + 8*a + 4*hi) = ow;
        }
    }
    if (hi == 0) pml[base] = make_float2(m_run, lt);
}

// ------------------------------------------------------------------
// Combine the 4 split-K partials. (unchanged; handles m_s >= 0 init)
// ------------------------------------------------------------------
__global__ __launch_bounds__(256) void gat_comb(
    const _Float16* __restrict__ po, const float2* __restrict__ pml,
    float* __restrict__ out)
{
    int gid = blockIdx.x * 256 + threadIdx.x;
    int row = gid >> 2;
    int col = (gid & 3) * 16;
    float2 ml[4];
    float Mx = MASKV;
    #pragma unroll
    for (int s = 0; s < 4; ++s) {
        ml[s] = pml[s * (BATCH * NN) + row];
        Mx = fmaxf(Mx, ml[s].x);
    }
    float w[4], den = 0.f;
    #pragma unroll
    for (int s = 0; s < 4; ++s) {
        w[s] = __builtin_amdgcn_exp2f(ml[s].x - Mx);
        den += w[s] * ml[s].y;
    }
    float inv = 1.0f / den;
    float acc[16] = {};
    #pragma unroll
    for (int s = 0; s < 4; ++s) {
        const _Float16* p = po + ((size_t)s * (BATCH * NN) + row) * 64 + col;
        float a = w[s] * inv;
        half8 v0 = *(const half8*)(p);
        half8 v1 = *(const half8*)(p + 8);
        #pragma unroll
        for (int j = 0; j < 8; ++j) {
            acc[j]     += a * (float)v0[j];
            acc[j + 8] += a * (float)v1[j];
        }
    }
    float* op = out + (size_t)row * 64 + col;
    #pragma unroll
    for (int i = 0; i < 4; ++i) {
        f32x4 r = {acc[4*i], acc[4*i+1], acc[4*i+2], acc[4*i+3]};
        *(f32x4*)(op + i*4) = r;
    }
}

extern "C" void kernel_launch(void* const* d_in, const int* in_sizes, int n_in,
                              void* d_out, int out_size, void* d_ws, size_t ws_size,
                              hipStream_t stream) {
    const float* X  = (const float*)d_in[0];
    const int*   A  = (const int*)d_in[1];
    const float* W0 = (const float*)d_in[2];
    const float* Wq = (const float*)d_in[3];
    const float* Wk = (const float*)d_in[4];
    float* out = (float*)d_out;
    char* ws = (char*)d_ws;
    const size_t SZ = (size_t)BATCH * NN * CC * 2;        // 4 MB per fp16 tensor
    _Float16* qh  = (_Float16*)(ws);
    _Float16* kbf = (_Float16*)(ws + SZ);
    _Float16* vtb = (_Float16*)(ws + 2*SZ);
    char* Mbase = ws + 3*SZ;                               // 2 MB mask
    _Float16* po = (_Float16*)(Mbase + 2*1024*1024);       // 16 MB
    float2* pml  = (float2*)(Mbase + 2*1024*1024 + 4*SZ);  // 1 MB

    hipLaunchKernelGGL(gat_proj, dim3(512),  dim3(256), 0, stream, X, W0, Wq, Wk, qh, kbf, vtb);
    hipLaunchKernelGGL(gat_mask, dim3(4096), dim3(256), 0, stream, A, (unsigned short*)Mbase);
    hipLaunchKernelGGL(gat_attn, dim3(1024), dim3(256), 0, stream, qh, kbf, vtb,
                       (const unsigned long long*)Mbase, po, pml);
    hipLaunchKernelGGL(gat_comb, dim3(512),  dim3(256), 0, stream, po, pml, out);
}

// Round 7
// 194.428 us; speedup vs baseline: 1.0779x; 1.0245x over previous
//
#include <hip/hip_runtime.h>
#include <stdint.h>

#define BATCH 8
#define NN 4096
#define CC 64
#define MASKV -1.0e30f
#define LOG2E 1.4426950408889634f

typedef _Float16 half8 __attribute__((ext_vector_type(8)));
typedef __fp16 fp16x2 __attribute__((ext_vector_type(2)));
typedef float f32x4 __attribute__((ext_vector_type(4)));
typedef float f32x16 __attribute__((ext_vector_type(16)));

typedef __attribute__((address_space(1))) const unsigned int gu32;
typedef __attribute__((address_space(3))) unsigned int lu32;
// generic->AS(3): low 32 bits of a generic LDS pointer ARE the LDS offset
// (apertures are 4GiB-aligned); global flat address == AS(1) address.
#define GLL16(gp, lp) __builtin_amdgcn_global_load_lds( \
    (gu32*)(uintptr_t)(gp), (lu32*)(unsigned)(uintptr_t)(lp), 16, 0, 0)

__device__ __forceinline__ unsigned pk_rtz(float a, float b) {
    union { fp16x2 h; unsigned u; } r;
    r.h = __builtin_amdgcn_cvt_pkrtz(a, b);
    return r.u;
}

// ------------------------------------------------------------------
// Fused prep: blocks 0-511 = projection (q fp16 pre-scaled by log2e,
// k fp16, vT fp16 [b][c][n]; split-compensated fp16 MFMA); blocks
// 512-4607 = adjacency bitmask (forced diagonal, compact 2 MB).
// ------------------------------------------------------------------
__global__ __launch_bounds__(256) void gat_prep(
    const float* __restrict__ X, const float* __restrict__ W0,
    const float* __restrict__ Wq, const float* __restrict__ Wk,
    const int* __restrict__ A,
    _Float16* __restrict__ qh, _Float16* __restrict__ kb,
    _Float16* __restrict__ vt, unsigned short* __restrict__ M16)
{
    __shared__ alignas(16) _Float16 WTh[3][64][72];
    __shared__ alignas(16) _Float16 WTl[3][64][72];
    const int t = threadIdx.x;
    if (blockIdx.x >= 512) {                       // ---- mask part
        const int row = blockIdx.x - 512;
        const int4* ap = (const int4*)(A + (size_t)row * NN + t * 16);
        unsigned m = 0;
        #pragma unroll
        for (int j = 0; j < 4; ++j) {
            int4 a = ap[j];
            m |= (a.x != 0 ? 1u : 0u) << (4*j);
            m |= (a.y != 0 ? 1u : 0u) << (4*j + 1);
            m |= (a.z != 0 ? 1u : 0u) << (4*j + 2);
            m |= (a.w != 0 ? 1u : 0u) << (4*j + 3);
        }
        if (t == (row >> 4)) m |= 1u << (row & 15);
        M16[(size_t)row * 256 + t] = (unsigned short)m;
        return;
    }
    // ---- projection part
    const float* Ws[3] = {W0, Wq, Wk};
    for (int e = t; e < 4096; e += 256) {
        int k = e >> 6, c = e & 63;
        #pragma unroll
        for (int m = 0; m < 3; ++m) {
            float w = Ws[m][e];
            _Float16 hi = (_Float16)w;
            WTh[m][c][k] = hi;
            WTl[m][c][k] = (_Float16)(w - (float)hi);
        }
    }
    __syncthreads();
    const int lane = t & 63, wv = t >> 6;
    const int cl = lane & 15, g = lane >> 4;
    int tile = blockIdx.x * 4 + wv;
    int gr = tile * 16;
    const float* xr = X + (size_t)(gr + cl) * CC;
    half8 xh[2], xl[2];
    #pragma unroll
    for (int kf = 0; kf < 2; ++kf) {
        f32x4 a0 = *(const f32x4*)(xr + g*8 + kf*32);
        f32x4 a1 = *(const f32x4*)(xr + g*8 + kf*32 + 4);
        half8 h, l;
        #pragma unroll
        for (int j = 0; j < 4; ++j) {
            _Float16 h0 = (_Float16)a0[j], h1 = (_Float16)a1[j];
            h[j]   = h0; l[j]   = (_Float16)(a0[j] - (float)h0);
            h[j+4] = h1; l[j+4] = (_Float16)(a1[j] - (float)h1);
        }
        xh[kf] = h; xl[kf] = l;
    }
    #pragma unroll
    for (int mat = 1; mat <= 2; ++mat) {
        #pragma unroll
        for (int nt = 0; nt < 4; ++nt) {
            f32x4 acc = {0.f, 0.f, 0.f, 0.f};
            #pragma unroll
            for (int kf = 0; kf < 2; ++kf) {
                half8 bh = *(const half8*)&WTh[mat][nt*16 + cl][g*8 + kf*32];
                half8 bl = *(const half8*)&WTl[mat][nt*16 + cl][g*8 + kf*32];
                acc = __builtin_amdgcn_mfma_f32_16x16x32_f16(xh[kf], bh, acc, 0, 0, 0);
                acc = __builtin_amdgcn_mfma_f32_16x16x32_f16(xl[kf], bh, acc, 0, 0, 0);
                acc = __builtin_amdgcn_mfma_f32_16x16x32_f16(xh[kf], bl, acc, 0, 0, 0);
            }
            #pragma unroll
            for (int i = 0; i < 4; ++i) {
                size_t off = (size_t)(gr + 4*g + i) * CC + nt*16 + cl;
                if (mat == 1) qh[off] = (_Float16)(acc[i] * LOG2E);
                else          kb[off] = (_Float16)acc[i];
            }
        }
    }
    {
        int b = gr >> 12, n0 = gr & (NN - 1);
        #pragma unroll
        for (int mt = 0; mt < 4; ++mt) {
            f32x4 acc = {0.f, 0.f, 0.f, 0.f};
            #pragma unroll
            for (int kf = 0; kf < 2; ++kf) {
                half8 ah = *(const half8*)&WTh[0][mt*16 + cl][g*8 + kf*32];
                half8 al = *(const half8*)&WTl[0][mt*16 + cl][g*8 + kf*32];
                acc = __builtin_amdgcn_mfma_f32_16x16x32_f16(ah, xh[kf], acc, 0, 0, 0);
                acc = __builtin_amdgcn_mfma_f32_16x16x32_f16(al, xh[kf], acc, 0, 0, 0);
                acc = __builtin_amdgcn_mfma_f32_16x16x32_f16(ah, xl[kf], acc, 0, 0, 0);
            }
            #pragma unroll
            for (int i = 0; i < 4; ++i) {
                int co = mt*16 + 4*g + i;
                vt[((size_t)b * CC + co) * NN + n0 + cl] = (_Float16)acc[i];
            }
        }
    }
}

// ------------------------------------------------------------------
// Flash attention, split-K x4 (32x32 structure) -- round-7 changes:
//  * global_load_lds staging (async DMA, pre-swizzled per-lane global
//    source + linear LDS dest): removes 4 ds_write_b128/thread, the
//    6-load VGPR round-trip, and the mid-iter vmcnt stall. Wave wv
//    stages region wv of {K rows 0-31, K 32-63, V 0-31, V 32-63};
//    src_col = ((l&7)*16) ^ ((l>>3)<<4) reproduces the read-side XOR.
//  * defer-max THR=8: skip o-rescale while masked max grows <= 8
//    (P bounded by 2^8; safe since po now stores NORMALIZED o/l).
//  * epilogue stores o/l in fp16 (better precision); comb weights
//    each split by w_s*l_s.
// ------------------------------------------------------------------
__global__ __launch_bounds__(256) void gat_attn(
    const _Float16* __restrict__ qg,
    const _Float16* __restrict__ kf16, const _Float16* __restrict__ vtb,
    const unsigned long long* __restrict__ M,
    _Float16* __restrict__ po, float2* __restrict__ pml)
{
    __shared__ alignas(16) _Float16 Kt[2][64][64];    // [buf][key][c_in], swizzled
    __shared__ alignas(16) _Float16 Vt[2][64][64];    // [buf][c_out][key], swizzled
    __shared__ alignas(8) uint2 LUT[16];              // nib -> 2 halfword AND-masks
    const int t = threadIdx.x;
    const int lane = t & 63, wv = t >> 6;
    const int q32 = lane & 31, hi = lane >> 5;
    const int blk = blockIdx.x;        // 1024
    const int b  = blk & 7;            // batch == XCD
    const int sp = (blk >> 3) & 3;     // key split
    const int qb = blk >> 5;           // q tile 0..31
    const int Q0 = qb * 128 + wv * 32;
    const int c0 = sp * 16;
    const int swz = (q32 & 7) << 4;    // read-side XOR (row%8)

    if (t < 16) {
        unsigned n = t;
        LUT[n] = make_uint2(((n & 1u) ? 0x0000FFFFu : 0u) | ((n & 2u) ? 0xFFFF0000u : 0u),
                            ((n & 4u) ? 0x0000FFFFu : 0u) | ((n & 8u) ? 0xFFFF0000u : 0u));
    }

    // ---- async staging setup (wave wv owns one 4KB region)
    const int lrow = lane >> 3;                          // 0..7
    const int lcol = ((lane & 7) * 16) ^ (lrow << 4);    // pre-swizzled byte col
    const bool isK = (wv < 2);
    const int seg = isK ? wv : (wv - 2);
    const char* gsrc0 = isK
        ? (const char*)(kf16 + (size_t)b * NN * CC)
            + (size_t)c0 * 8192 + (size_t)seg * 4096 + lrow * 128 + lcol
        : (const char*)(vtb + (size_t)b * CC * NN)
            + (size_t)c0 * 128 + ((size_t)(seg * 32 + lrow)) * 8192 + lcol;
    const int istride = isK ? 1024 : 65536;
    const int cstride = isK ? 8192 : 128;

    auto stage = [&](int rel, int bufi) {
        const char* s = gsrc0 + (size_t)rel * cstride;
        char* d = isK ? ((char*)&Kt[bufi][0][0] + seg * 4096)
                      : ((char*)&Vt[bufi][0][0] + seg * 4096);
        #pragma unroll
        for (int i = 0; i < 4; ++i)
            GLL16(s + i * istride, d + i * 1024);
    };
    auto pkmax = [](unsigned a, unsigned b) {
        unsigned d;
        asm("v_pk_max_f16 %0, %1, %2" : "=v"(d) : "v"(a), "v"(b));
        return d;
    };

    half8 qf[4];                                       // B-frag: c = kf*16 + hi*8 + j
    {
        const _Float16* qr = qg + ((size_t)b * NN + Q0 + q32) * CC + hi * 8;
        #pragma unroll
        for (int kf = 0; kf < 4; ++kf) qf[kf] = *(const half8*)(qr + kf * 16);
    }
    const unsigned long long* Mrow = M + (size_t)(Q0 + q32) * 64 + c0;

    f32x16 o0 = {}, o1 = {};
    float m_run = 0.f, l_run = 0.f;

    stage(0, 0);
    unsigned long long cm = Mrow[0];
    __syncthreads();                      // drains vmcnt, then barrier

    for (int kc = 0; kc < 16; ++kc) {
        const int cur = kc & 1;
        unsigned long long pmn = 0;
        if (kc < 15) {
            stage(kc + 1, cur ^ 1);       // async into other buffer
            pmn = Mrow[kc + 1];
        }

        // ---- QK: S^T[key][qrow]
        const char* kbase = (const char*)&Kt[cur][0][0] + q32 * 128;
        __builtin_amdgcn_s_setprio(1);
        f32x16 s0 = {}, s1 = {};
        #pragma unroll
        for (int kf = 0; kf < 4; ++kf) {
            const int col = (kf * 32 + hi * 16) ^ swz;
            half8 ka0 = *(const half8*)(kbase + col);
            half8 ka1 = *(const half8*)(kbase + 4096 + col);
            s0 = __builtin_amdgcn_mfma_f32_32x32x16_f16(ka0, qf[kf], s0, 0, 0, 0);
            s1 = __builtin_amdgcn_mfma_f32_32x32x16_f16(ka1, qf[kf], s1, 0, 0, 0);
        }
        __builtin_amdgcn_s_setprio(0);

        // ---- halfword AND masks via LDS LUT
        const unsigned wlo = (unsigned)cm, whi = (unsigned)(cm >> 32);
        unsigned hm[16];
        #pragma unroll
        for (int kt = 0; kt < 2; ++kt) {
            unsigned w = kt ? whi : wlo;
            #pragma unroll
            for (int a = 0; a < 4; ++a) {
                unsigned nib = (w >> (8 * a + 4 * hi)) & 15u;
                uint2 e = LUT[nib];
                hm[kt*8 + 2*a]     = e.x;
                hm[kt*8 + 2*a + 1] = e.y;
            }
        }
        // ---- masked raw-score max (packed fp16), clamp 0
        {
            unsigned sm[16];
            #pragma unroll
            for (int j = 0; j < 8; ++j) {
                sm[j]   = pk_rtz(s0[2*j], s0[2*j+1]) & hm[j];
                sm[8+j] = pk_rtz(s1[2*j], s1[2*j+1]) & hm[8+j];
            }
            unsigned u0 = pkmax(pkmax(pkmax(sm[0],sm[1]),  pkmax(sm[2],sm[3])),
                                pkmax(pkmax(sm[4],sm[5]),  pkmax(sm[6],sm[7])));
            unsigned u1 = pkmax(pkmax(pkmax(sm[8],sm[9]),  pkmax(sm[10],sm[11])),
                                pkmax(pkmax(sm[12],sm[13]),pkmax(sm[14],sm[15])));
            union { unsigned u; fp16x2 h; } tu; tu.u = pkmax(u0, u1);
            float mx = fmaxf(fmaxf((float)tu.h[0], (float)tu.h[1]), 0.f);
            mx = fmaxf(mx, __shfl_xor(mx, 32));        // partner half
            if (__any(mx > m_run + 8.0f)) {            // defer-max THR=8
                float nm = fmaxf(m_run, mx);
                float alpha = __builtin_amdgcn_exp2f(m_run - nm);
                m_run = nm;
                l_run *= alpha;
                #pragma unroll
                for (int i = 0; i < 16; ++i) { o0[i] *= alpha; o1[i] *= alpha; }
            }
        }
        // ---- p = exp2(leaky(s) - m), pack + mask
        unsigned wp[16];
        #pragma unroll
        for (int j = 0; j < 8; ++j) {
            float p0 = __builtin_amdgcn_exp2f(fmaxf(s0[2*j]   - m_run, fmaf(0.01f, s0[2*j],   -m_run)));
            float p1 = __builtin_amdgcn_exp2f(fmaxf(s0[2*j+1] - m_run, fmaf(0.01f, s0[2*j+1], -m_run)));
            float p2 = __builtin_amdgcn_exp2f(fmaxf(s1[2*j]   - m_run, fmaf(0.01f, s1[2*j],   -m_run)));
            float p3 = __builtin_amdgcn_exp2f(fmaxf(s1[2*j+1] - m_run, fmaf(0.01f, s1[2*j+1], -m_run)));
            wp[j]   = pk_rtz(p0, p1) & hm[j];
            wp[8+j] = pk_rtz(p2, p3) & hm[8+j];
        }
        // ---- l sum over own half (packed); pair-sum in epilogue
        {
            union { unsigned u; fp16x2 h; } z; z.u = 0u;
            fp16x2 acc = z.h;
            #pragma unroll
            for (int j4 = 0; j4 < 4; ++j4) {
                union { unsigned u; fp16x2 h; } x0, x1, x2, x3;
                x0.u = wp[4*j4]; x1.u = wp[4*j4+1]; x2.u = wp[4*j4+2]; x3.u = wp[4*j4+3];
                acc += (x0.h + x1.h) + (x2.h + x3.h);
            }
            l_run += (float)acc[0] + (float)acc[1];
        }
        // ---- redistribute P -> B-frag layout via shfl_xor(32)
        #pragma unroll
        for (int g4 = 0; g4 < 4; ++g4) {
            unsigned w0 = wp[4*g4+0], w1 = wp[4*g4+1];
            unsigned w2 = wp[4*g4+2], w3 = wp[4*g4+3];
            unsigned u = hi ? w0 : w2;
            unsigned v = hi ? w1 : w3;
            unsigned su = (unsigned)__shfl_xor((int)u, 32);
            unsigned sv = (unsigned)__shfl_xor((int)v, 32);
            wp[4*g4+0] = hi ? su : w0;
            wp[4*g4+1] = hi ? sv : w1;
            wp[4*g4+2] = hi ? w2 : su;
            wp[4*g4+3] = hi ? w3 : sv;
        }
        // ---- PV: O^T += V^T * P^T
        const char* vb = (const char*)&Vt[cur][0][0] + q32 * 128;
        __builtin_amdgcn_s_setprio(1);
        #pragma unroll
        for (int kc4 = 0; kc4 < 4; ++kc4) {
            union { unsigned u[4]; half8 h; } pb;
            pb.u[0] = wp[4*kc4+0]; pb.u[1] = wp[4*kc4+1];
            pb.u[2] = wp[4*kc4+2]; pb.u[3] = wp[4*kc4+3];
            const int col = (kc4 * 32 + hi * 16) ^ swz;
            half8 vf0 = *(const half8*)(vb + col);
            half8 vf1 = *(const half8*)(vb + 4096 + col);
            o0 = __builtin_amdgcn_mfma_f32_32x32x16_f16(vf0, pb.h, o0, 0, 0, 0);
            o1 = __builtin_amdgcn_mfma_f32_32x32x16_f16(vf1, pb.h, o1, 0, 0, 0);
        }
        __builtin_amdgcn_s_setprio(0);
        cm = pmn;
        if (kc < 15) __syncthreads();     // drains gll vmcnt + barrier
    }

    // epilogue: NORMALIZED fp16 partial o/l + (m, l) for combine
    float lt = l_run + __shfl_xor(l_run, 32);
    float invl = (lt > 0.f) ? 1.0f / lt : 0.f;
    size_t base = (size_t)sp * (BATCH * NN) + (size_t)b * NN + Q0 + q32;
    _Float16* orow = po + base * 64;
    #pragma unroll
    for (int a = 0; a < 4; ++a) {
        {
            uint2 ow = { pk_rtz(o0[4*a] * invl, o0[4*a+1] * invl),
                         pk_rtz(o0[4*a+2] * invl, o0[4*a+3] * invl) };
            *(uint2*)(orow + 8*a + 4*hi) = ow;
        }
        {
            uint2 ow = { pk_rtz(o1[4*a] * invl, o1[4*a+1] * invl),
                         pk_rtz(o1[4*a+2] * invl, o1[4*a+3] * invl) };
            *(uint2*)(orow + 32 + 8*a + 4*hi) = ow;
        }
    }
    if (hi == 0) pml[base] = make_float2(m_run, lt);
}

// ------------------------------------------------------------------
// Combine the 4 split-K partials: po holds NORMALIZED o/l, so
// out = sum_s (w_s*l_s) * o_norm_s / sum_s (w_s*l_s).
// ------------------------------------------------------------------
__global__ __launch_bounds__(256) void gat_comb(
    const _Float16* __restrict__ po, const float2* __restrict__ pml,
    float* __restrict__ out)
{
    int gid = blockIdx.x * 256 + threadIdx.x;
    int row = gid >> 2;
    int col = (gid & 3) * 16;
    float2 ml[4];
    float Mx = MASKV;
    #pragma unroll
    for (int s = 0; s < 4; ++s) {
        ml[s] = pml[s * (BATCH * NN) + row];
        Mx = fmaxf(Mx, ml[s].x);
    }
    float w[4], den = 0.f;
    #pragma unroll
    for (int s = 0; s < 4; ++s) {
        w[s] = __builtin_amdgcn_exp2f(ml[s].x - Mx) * ml[s].y;  // w_s * l_s
        den += w[s];
    }
    float inv = 1.0f / den;                        // diag guarantees den > 0
    float acc[16] = {};
    #pragma unroll
    for (int s = 0; s < 4; ++s) {
        const _Float16* p = po + ((size_t)s * (BATCH * NN) + row) * 64 + col;
        float a = w[s] * inv;
        half8 v0 = *(const half8*)(p);
        half8 v1 = *(const half8*)(p + 8);
        #pragma unroll
        for (int j = 0; j < 8; ++j) {
            acc[j]     += a * (float)v0[j];
            acc[j + 8] += a * (float)v1[j];
        }
    }
    float* op = out + (size_t)row * 64 + col;
    #pragma unroll
    for (int i = 0; i < 4; ++i) {
        f32x4 r = {acc[4*i], acc[4*i+1], acc[4*i+2], acc[4*i+3]};
        *(f32x4*)(op + i*4) = r;
    }
}

extern "C" void kernel_launch(void* const* d_in, const int* in_sizes, int n_in,
                              void* d_out, int out_size, void* d_ws, size_t ws_size,
                              hipStream_t stream) {
    const float* X  = (const float*)d_in[0];
    const int*   A  = (const int*)d_in[1];
    const float* W0 = (const float*)d_in[2];
    const float* Wq = (const float*)d_in[3];
    const float* Wk = (const float*)d_in[4];
    float* out = (float*)d_out;
    char* ws = (char*)d_ws;
    const size_t SZ = (size_t)BATCH * NN * CC * 2;        // 4 MB per fp16 tensor
    _Float16* qh  = (_Float16*)(ws);
    _Float16* kbf = (_Float16*)(ws + SZ);
    _Float16* vtb = (_Float16*)(ws + 2*SZ);
    char* Mbase = ws + 3*SZ;                               // 2 MB mask
    _Float16* po = (_Float16*)(Mbase + 2*1024*1024);       // 16 MB
    float2* pml  = (float2*)(Mbase + 2*1024*1024 + 4*SZ);  // 1 MB

    hipLaunchKernelGGL(gat_prep, dim3(4608), dim3(256), 0, stream,
                       X, W0, Wq, Wk, A, qh, kbf, vtb, (unsigned short*)Mbase);
    hipLaunchKernelGGL(gat_attn, dim3(1024), dim3(256), 0, stream, qh, kbf, vtb,
                       (const unsigned long long*)Mbase, po, pml);
    hipLaunchKernelGGL(gat_comb, dim3(512),  dim3(256), 0, stream, po, pml, out);
}